// Round 4
// baseline (1174.188 us; speedup 1.0000x reference)
//
#include <hip/hip_runtime.h>
#include <hip/hip_bf16.h>
#include <hip/hip_fp16.h>

typedef __hip_bfloat16 bf16;
typedef unsigned short ushort_t;
typedef unsigned short us8 __attribute__((ext_vector_type(8)));
typedef _Float16 half8 __attribute__((ext_vector_type(8)));
typedef float f32x4 __attribute__((ext_vector_type(4)));

#define NEG 0.2f
#define LNEPS 1e-5f
#define BWD 512                 // CSR bucket width (nodes)
#define SEGS 4                  // neighbor-ID segments (range-based, ~3.2MB slices)
#define SEGS_LOG 2
#define MAXNPB 104              // max nodes per block in persistent gather

__device__ __forceinline__ int plaus(unsigned int lo){
    lo &= 0x7FFFu;
    if (lo == 0) return 1;
    unsigned int ex = (lo >> 7) & 0xFF;
    return (ex >= 100 && ex <= 140) ? 1 : 0;
}

__device__ __forceinline__ float decode_slot(const ushort_t* s, long long i, int fl){
    long long base = i << fl;
    unsigned int hi = s[base + fl];
    unsigned int lo = s[base];
    unsigned int bits = (hi << 16) | (lo * (unsigned int)fl);
    return __uint_as_float(bits);
}

// ---------- per-tensor dtype flags ----------
__global__ void k_detect(const void* t0, const void* t1, const void* t2, const void* t3,
                         const void* t4, const void* t5, const void* t6, const void* t7,
                         const void* t8, const void* lng, int* flags){
    int t = threadIdx.x;
    if (blockIdx.x != 0) return;
    if (t < 9){
        const void* ptrs[9] = {t0,t1,t2,t3,t4,t5,t6,t7,t8};
        const ushort_t* w = (const ushort_t*)ptrs[t];
        int all_bf = 1;
        for (int i = 0; i < 16; i++) all_bf &= plaus((unsigned int)w[i]);
        flags[t] = all_bf ? 0 : 1;
    } else if (t == 9){
        const ushort_t* w = (const ushort_t*)lng;
        flags[9] = (w[0] == 0x3F80u) ? 0 : 1;
    }
}

// ---------- stage params ----------
#define P_TOTAL 56577
__global__ void k_convert(const void* p0, const void* p1, const void* p2, const void* p3,
        const void* p4, const void* p5, const void* p6, const void* p7, const void* p8,
        const void* p9, const void* p10, const void* p11, const void* p12, const void* p13,
        const void* p14, const int* flags, float* P){
    int idx = blockIdx.x*blockDim.x + threadIdx.x;
    if (idx >= P_TOTAL) return;
    const int sizes[15] = {4096,64,12288,12288,192,192,192,24576,192,192,192,2048,32,32,1};
    const int fidx[15]  = {1,  -1,  2,    3,    4,  5,  -1, 6,    -1, 9,  -1, 7,   -1,8, -1};
    const void* ptrs[15] = {p0,p1,p2,p3,p4,p5,p6,p7,p8,p9,p10,p11,p12,p13,p14};
    int s = 0, base = 0;
    while (idx - base >= sizes[s]){ base += sizes[s]; s++; }
    int li = idx - base;
    int fi = fidx[s];
    int fl = (fi >= 0) ? flags[fi] : 0;
    P[idx] = decode_slot((const ushort_t*)ptrs[s], li, fl);
}

// ---------- bucketed CSR build ----------
__global__ __launch_bounds__(1024) void kb_hist(const int* __restrict__ row,
        const int* __restrict__ col, int* __restrict__ bcnt, int NBK, int E){
    __shared__ int lh[512];
    int t = threadIdx.x;
    for (int i = t; i < 2*NBK; i += 1024) lh[i] = 0;
    __syncthreads();
    for (long long e = (long long)blockIdx.x*1024 + t; e < E; e += (long long)gridDim.x*1024){
        atomicAdd(&lh[row[e] >> 9], 1);
        atomicAdd(&lh[NBK + (col[e] >> 9)], 1);
    }
    __syncthreads();
    for (int i = t; i < 2*NBK; i += 1024){
        int v = lh[i];
        if (v) atomicAdd(&bcnt[i], v);
    }
}

__global__ __launch_bounds__(256) void kb_scan(const int* __restrict__ bcnt,
        int* __restrict__ bptr_r, int* __restrict__ bptr_c,
        int* __restrict__ bcur_r, int* __restrict__ bcur_c, int NBK, int E){
    __shared__ int sh[256];
    int side = blockIdx.x;
    const int* c = bcnt + side*NBK;
    int* bp = side ? bptr_c : bptr_r;
    int* bc = side ? bcur_c : bcur_r;
    int t = threadIdx.x;
    int v = (t < NBK) ? c[t] : 0;
    sh[t] = v; __syncthreads();
    for (int off = 1; off < 256; off <<= 1){
        int add = (t >= off) ? sh[t-off] : 0;
        __syncthreads();
        sh[t] += add;
        __syncthreads();
    }
    if (t < NBK){ int e = sh[t] - v; bp[t] = e; bc[t] = e; }
    if (t == 0) bp[NBK] = E;
}

__global__ __launch_bounds__(1024) void kb_bin(const int* __restrict__ key,
        const int* __restrict__ pay, int* __restrict__ bcur,
        uint2* __restrict__ stage, int NBK, int E){
    __shared__ int lh[256], lbase[256];
    int t = threadIdx.x;
    for (long long tile = (long long)blockIdx.x*1024; tile < E; tile += (long long)gridDim.x*1024){
        for (int i = t; i < NBK; i += 1024) lh[i] = 0;
        __syncthreads();
        int e = (int)tile + t;
        int k = 0, p = 0, b = -1, rank = 0;
        if (e < E){
            k = key[e]; p = pay[e]; b = k >> 9;
            rank = atomicAdd(&lh[b], 1);
        }
        __syncthreads();
        for (int i = t; i < NBK; i += 1024){
            int c = lh[i];
            lbase[i] = c ? atomicAdd(&bcur[i], c) : 0;
        }
        __syncthreads();
        if (b >= 0) stage[lbase[b] + rank] = make_uint2((unsigned)k, (unsigned)p);
        __syncthreads();
    }
}

// place with per-(node,segment) sub-lists: ptr4[node*SEGS+s] .. ptr4[node*SEGS+s+1]
// holds neighbors whose ID/segw == s (range-based: even ~3.2MB table slices).
__global__ __launch_bounds__(1024) void kb_place(const uint2* __restrict__ stage,
        const int* __restrict__ bptr, int* __restrict__ ptr4, int* __restrict__ outarr,
        float* __restrict__ dinv, int wantdinv, int N, int E, int segw){
    __shared__ int lcnt4[BWD*SEGS];
    __shared__ int lpos4[BWD*SEGS];
    __shared__ int lns[BWD], lsc[BWD];
    int b = blockIdx.x;
    int s = bptr[b], e = bptr[b+1];
    int nbase = b << 9;
    int t = threadIdx.x;
    for (int i = t; i < BWD*SEGS; i += 1024) lcnt4[i] = 0;
    __syncthreads();
    for (int i = s + t; i < e; i += 1024){
        uint2 rec = stage[i];
        int key = (((int)rec.x - nbase) << SEGS_LOG) | (int)(rec.y / (unsigned)segw);
        atomicAdd(&lcnt4[key], 1);
    }
    __syncthreads();
    if (t < BWD){
        int tot = 0;
        #pragma unroll
        for (int g = 0; g < SEGS; g++) tot += lcnt4[t*SEGS+g];
        lns[t] = tot;
        lsc[t] = tot;
    }
    __syncthreads();
    for (int off = 1; off < BWD; off <<= 1){
        int add = (t >= off && t < BWD) ? lsc[t-off] : 0;
        __syncthreads();
        if (t < BWD) lsc[t] += add;
        __syncthreads();
    }
    if (t < BWD){
        int node = nbase + t;
        int tot = lns[t];
        int p = lsc[t] - tot;               // node-exclusive prefix within bucket
        #pragma unroll
        for (int g = 0; g < SEGS; g++){
            lpos4[t*SEGS+g] = p;
            if (node < N) ptr4[(size_t)node*SEGS + g] = s + p;
            p += lcnt4[t*SEGS+g];
        }
        if (node < N && wantdinv) dinv[node] = tot > 0 ? rsqrtf((float)tot) : 0.f;
    }
    if (b == 0 && t == 0) ptr4[(size_t)N*SEGS] = E;
    __syncthreads();
    for (int i = s + t; i < e; i += 1024){
        uint2 rec = stage[i];
        int key = (((int)rec.x - nbase) << SEGS_LOG) | (int)(rec.y / (unsigned)segw);
        int pos = s + atomicAdd(&lpos4[key], 1);
        outarr[pos] = (int)rec.y;
    }
}

// ---------- precompute fused weights ----------
__global__ void k_prew(const float* __restrict__ fus_W, const float* __restrict__ e8_W,
                       const float* __restrict__ gat_b, const float* __restrict__ fus_b,
                       float* __restrict__ W1c, float* __restrict__ b2c){
    int t = blockIdx.x*blockDim.x + threadIdx.x;
    if (t < 3*4096){
        int i = t >> 12, jq = t & 4095, j = jq >> 6, q = jq & 63;
        const float* fw = fus_W + (size_t)i*64*128 + (size_t)j*128;
        const float* ew = e8_W + (size_t)i*4096;
        float acc = 0.f;
        for (int p = 0; p < 64; p++) acc += fw[p] * ew[p*64+q];
        W1c[t] = acc;
    }
    if (t < 3*64){
        int i = t >> 6, j = t & 63;
        const float* fw = fus_W + (size_t)i*64*128 + (size_t)j*128 + 64;
        float acc = fus_b[i*64+j];
        for (int p = 0; p < 64; p++) acc += gat_b[i*64+p] * fw[p];
        b2c[t] = acc;
    }
}

// ---------- pre-swizzle fusion weights into MFMA B-fragment order (fp16) ----------
__global__ void k_prewB(const float* __restrict__ W1c, const float* __restrict__ fus_W,
                        _Float16* __restrict__ Bfrag){
    int idx = blockIdx.x*blockDim.x + threadIdx.x;
    if (idx >= 3*8192) return;
    int i = idx / 8192; int rem = idx & 8191;
    int j = rem & 7, lane = (rem >> 3) & 63, kk = (rem >> 9) & 3, t = rem >> 11;
    int k = kk*32 + (lane >> 4)*8 + j;
    int n = t*16 + (lane & 15);
    float v = (k < 64) ? W1c[i*4096 + n*64 + k]
                       : fus_W[(size_t)i*8192 + n*128 + 64 + (k - 64)];
    Bfrag[idx] = (_Float16)v;
}

// ---------- pre-swizzle gat_W into B-frag order ----------
__global__ void k_prewBg(const float* __restrict__ gat_W, _Float16* __restrict__ Bg){
    int idx = blockIdx.x*blockDim.x + threadIdx.x;
    if (idx >= 3*4096) return;
    int i = idx / 4096; int rem = idx & 4095;
    int j = rem & 7, lane = (rem >> 3) & 63, kk = (rem >> 9) & 1, t = rem >> 10;
    int k = kk*32 + (lane >> 4)*8 + j;
    int n = t*16 + (lane & 15);
    Bg[idx] = (_Float16)gat_W[(size_t)i*4096 + k*64 + n];
}

// ---------- embedding ----------
__global__ __launch_bounds__(256) void k_embed(const ushort_t* __restrict__ xs,
        const int* __restrict__ flags, const float* __restrict__ W,
        const float* __restrict__ b, const float* __restrict__ dinv,
        float* __restrict__ h, __half* __restrict__ h16, __half* __restrict__ ht16, int N){
    __shared__ float Wt[64*64];
    for (int idx = threadIdx.x; idx < 4096; idx += 256){
        int k = idx >> 6, j = idx & 63;
        Wt[idx] = W[j*64+k];
    }
    __syncthreads();
    int fl = flags[0];
    int lane = threadIdx.x & 63;
    int wid  = (blockIdx.x*blockDim.x + threadIdx.x) >> 6;
    int nw   = (gridDim.x*blockDim.x) >> 6;
    float bj = b[lane];
    for (int v = wid; v < N; v += nw){
        float xj = decode_slot(xs, (long long)v*64 + lane, fl);
        float acc = bj;
        #pragma unroll
        for (int k = 0; k < 64; k++) acc += __shfl(xj, k) * Wt[k*64+lane];
        h[(size_t)v*64 + lane] = acc;
        h16[(size_t)v*64 + lane] = __float2half(acc);
        ht16[(size_t)v*64 + lane] = __float2half(dinv[v]*acc);
    }
}

// ---------- per-layer (MFMA): G16 = h16 @ gat_W, head sums a_s/a_d ----------
__global__ __launch_bounds__(256) void k_gat_g(const __half* __restrict__ h16,
        const _Float16* __restrict__ Bg, const float* __restrict__ att_src,
        const float* __restrict__ att_dst, __half* __restrict__ G16,
        float* __restrict__ a_s, float* __restrict__ a_d, int N){
    int lane = threadIdx.x & 63;
    int q = lane >> 4, c = lane & 15;
    half8 B[4][2];
    const half8* Bp = (const half8*)Bg;
    #pragma unroll
    for (int t = 0; t < 4; t++)
        #pragma unroll
        for (int kk = 0; kk < 2; kk++)
            B[t][kk] = Bp[(t*2+kk)*64 + lane];
    float asv[4], adv[4];
    #pragma unroll
    for (int t = 0; t < 4; t++){
        asv[t] = att_src[t*16 + c];
        adv[t] = att_dst[t*16 + c];
    }
    int tiles = (N + 15) >> 4;
    int wid = (blockIdx.x*blockDim.x + threadIdx.x) >> 6;
    int nw  = (gridDim.x*blockDim.x) >> 6;
    for (int tile = wid; tile < tiles; tile += nw){
        int nb = tile << 4;
        int anode = nb + c; if (anode >= N) anode = N - 1;
        const half8* ap = (const half8*)(h16 + (size_t)anode*64);
        half8 A0 = ap[q];
        half8 A1 = ap[4 + q];
        f32x4 acc[4];
        #pragma unroll
        for (int t = 0; t < 4; t++){
            f32x4 z = {0.f, 0.f, 0.f, 0.f};
            z = __builtin_amdgcn_mfma_f32_16x16x32_f16(A0, B[t][0], z, 0, 0, 0);
            z = __builtin_amdgcn_mfma_f32_16x16x32_f16(A1, B[t][1], z, 0, 0, 0);
            acc[t] = z;
        }
        #pragma unroll
        for (int r = 0; r < 4; r++){
            int node = nb + q*4 + r;
            float tsv[4], tdv[4];
            #pragma unroll
            for (int t = 0; t < 4; t++){
                float s1 = acc[t][r]*asv[t];
                float s2 = acc[t][r]*adv[t];
                #pragma unroll
                for (int o = 1; o < 16; o <<= 1){
                    s1 += __shfl_xor(s1, o);
                    s2 += __shfl_xor(s2, o);
                }
                tsv[t] = s1; tdv[t] = s2;
            }
            if (node < N){
                #pragma unroll
                for (int t = 0; t < 4; t++)
                    G16[(size_t)node*64 + t*16 + c] = __float2half(acc[t][r]);
                if (c == 0){
                    #pragma unroll
                    for (int t = 0; t < 4; t++){
                        a_s[node*4+t] = tsv[t];
                        a_d[node*4+t] = tdv[t];
                    }
                }
            }
        }
    }
}

// ---------- per-head global maxes ----------
__global__ __launch_bounds__(256) void k_headmax1(const float* __restrict__ a_s,
        const float* __restrict__ a_d, float* __restrict__ bmax_s,
        float* __restrict__ bmax_d, int n4){
    __shared__ float shs[256], shd[256];
    int t = threadIdx.x;
    int S = gridDim.x * 256;
    float ms = -1e30f, md = -1e30f;
    for (int i = blockIdx.x*256 + t; i < n4; i += S){
        ms = fmaxf(ms, a_s[i]); md = fmaxf(md, a_d[i]);
    }
    shs[t] = ms; shd[t] = md; __syncthreads();
    for (int off = 128; off >= 4; off >>= 1){
        if (t < off){ shs[t] = fmaxf(shs[t], shs[t+off]); shd[t] = fmaxf(shd[t], shd[t+off]); }
        __syncthreads();
    }
    if (t < 4){ bmax_s[blockIdx.x*4+t] = shs[t]; bmax_d[blockIdx.x*4+t] = shd[t]; }
}
__global__ void k_headmax2(const float* __restrict__ bmax_s, const float* __restrict__ bmax_d,
                           float* __restrict__ mxs, int nb){
    int t = threadIdx.x;
    if (blockIdx.x != 0 || t >= 8) return;
    const float* src = (t < 4) ? bmax_s : bmax_d;
    int hh = t & 3;
    float m = -1e30f;
    for (int i = 0; i < nb; i++) m = fmaxf(m, src[i*4+hh]);
    mxs[t] = m;
}

__device__ __forceinline__ float leaky(float t){ return t > 0.f ? t : NEG*t; }

// ---------- gather v4.1: segment-major, 2 nodes/wave x 4 edge-slots, LDS accumulators ----
// (v4 had 1024-stride zeroing + unlooped finalize with 256-thread blocks -> 3/4 of
//  acc unzeroed and nodes 32..97 never finalized. Fixed: stride 256, looped finalize.)
__global__ __launch_bounds__(256, 4) void k_gather(const __half* __restrict__ ht16,
        const __half* __restrict__ G16,
        const float* __restrict__ a_s, const float* __restrict__ a_d,
        const float* __restrict__ mxs, const float* __restrict__ dinv,
        const int* __restrict__ ptr4_r, const int* __restrict__ re_col,
        const int* __restrict__ ptr4_c, const int* __restrict__ ce_row,
        __half* __restrict__ Aj16, __half* __restrict__ xg16, int N, int npb){
    __shared__ float acc[MAXNPB][72];     // [node][0..63]=channels, [64..67]=ssum heads
    int bstart = blockIdx.x * npb;
    int t = threadIdx.x;
    int lane = t & 63;
    int w = t >> 6;                // wave 0..3
    int g = lane >> 5;             // node-half 0/1
    int slot = (lane >> 3) & 3;    // edge slot 0..3
    int sub = lane & 7;            // 8-channel chunk
    int hh = sub >> 1;             // head
    int nvis = (npb + 7) >> 3;     // 8 nodes per visit-round (4 waves x 2)
    int nzero = npb * 72;
    const us8* htb = (const us8*)ht16;
    const us8* gb  = (const us8*)G16;

    // ================= phase R: E8 aggregation (sum ht16[col]) =================
    for (int i = t; i < nzero; i += 256) ((float*)acc)[i] = 0.f;
    __syncthreads();
    for (int seg = 0; seg < SEGS; seg++){
        int lnc = w*2 + g;
        int vc  = bstart + lnc;
        bool onc = (lnc < npb) && (vc < N);
        int ib = onc ? ptr4_r[(size_t)vc*SEGS + seg] : 0;
        int ie = onc ? ptr4_r[(size_t)vc*SEGS + seg + 1] : 0;
        for (int vis = 0; vis < nvis; vis++){
            int lnn = lnc + 8, vn = vc + 8;
            bool onn = (vis+1 < nvis) && (lnn < npb) && (vn < N);
            int nib = onn ? ptr4_r[(size_t)vn*SEGS + seg] : 0;
            int nie = onn ? ptr4_r[(size_t)vn*SEGS + seg + 1] : 0;

            float part[8];
            #pragma unroll
            for (int j = 0; j < 8; j++) part[j] = 0.f;
            for (int i0 = ib; i0 < ie; i0 += 4){
                int ii = i0 + slot;
                bool val = ii < ie;
                int cix = re_col[val ? ii : ie - 1];
                float wt = val ? 1.f : 0.f;
                us8 q = htb[(size_t)cix*8 + sub];
                #pragma unroll
                for (int j = 0; j < 8; j++)
                    part[j] += wt * __half2float(__ushort_as_half(q[j]));
            }
            #pragma unroll
            for (int j = 0; j < 8; j++){
                part[j] += __shfl_xor(part[j], 8);
                part[j] += __shfl_xor(part[j], 16);
            }
            if (onc && slot == 0){
                float* row = acc[lnc];
                #pragma unroll
                for (int j = 0; j < 8; j++) row[sub*8 + j] += part[j];
            }
            lnc = lnn; vc = vn; onc = onn; ib = nib; ie = nie;
        }
    }
    __syncthreads();
    // finalize R: 8 threads per node, looped over all npb nodes
    for (int idx = t; idx < npb*8; idx += 256){
        int n0 = idx >> 3, sb = idx & 7;
        int v = bstart + n0;
        if (v < N){
            float dv = dinv[v];
            us8 pa;
            #pragma unroll
            for (int j = 0; j < 8; j++)
                pa[j] = __half_as_ushort(__float2half(dv * acc[n0][sb*8+j]));
            ((us8*)Aj16)[(size_t)v*8 + sb] = pa;
        }
    }
    __syncthreads();

    // ================= phase C: GAT aggregation (sum e*G16[row]) ================
    for (int i = t; i < nzero; i += 256) ((float*)acc)[i] = 0.f;
    __syncthreads();
    float sh = leaky(mxs[hh] + mxs[4+hh]);
    for (int seg = 0; seg < SEGS; seg++){
        int lnc = w*2 + g;
        int vc  = bstart + lnc;
        bool onc = (lnc < npb) && (vc < N);
        int ib = onc ? ptr4_c[(size_t)vc*SEGS + seg] : 0;
        int ie = onc ? ptr4_c[(size_t)vc*SEGS + seg + 1] : 0;
        float adv = onc ? a_d[(size_t)vc*4 + hh] : 0.f;
        for (int vis = 0; vis < nvis; vis++){
            int lnn = lnc + 8, vn = vc + 8;
            bool onn = (vis+1 < nvis) && (lnn < npb) && (vn < N);
            int nib = onn ? ptr4_c[(size_t)vn*SEGS + seg] : 0;
            int nie = onn ? ptr4_c[(size_t)vn*SEGS + seg + 1] : 0;
            float nadv = onn ? a_d[(size_t)vn*4 + hh] : 0.f;

            float part[8], psum = 0.f;
            #pragma unroll
            for (int j = 0; j < 8; j++) part[j] = 0.f;
            for (int i0 = ib; i0 < ie; i0 += 4){
                int ii = i0 + slot;
                bool val = ii < ie;
                int rix = ce_row[val ? ii : ie - 1];
                float e = __expf(leaky(a_s[(size_t)rix*4 + hh] + adv) - sh);
                e = val ? e : 0.f;
                us8 q = gb[(size_t)rix*8 + sub];
                #pragma unroll
                for (int j = 0; j < 8; j++)
                    part[j] += e * __half2float(__ushort_as_half(q[j]));
                psum += e;
            }
            #pragma unroll
            for (int j = 0; j < 8; j++){
                part[j] += __shfl_xor(part[j], 8);
                part[j] += __shfl_xor(part[j], 16);
            }
            psum += __shfl_xor(psum, 8);
            psum += __shfl_xor(psum, 16);
            if (onc && slot == 0){
                float* row = acc[lnc];
                #pragma unroll
                for (int j = 0; j < 8; j++) row[sub*8 + j] += part[j];
                if ((sub & 1) == 0 && (sub >> 1) == hh && sub == hh*2)
                    row[64 + hh] += psum;
            }
            lnc = lnn; vc = vn; onc = onn; ib = nib; ie = nie; adv = nadv;
        }
    }
    __syncthreads();
    // finalize C: self-loop + normalize, 8 threads per node, looped over all npb nodes
    for (int idx = t; idx < npb*8; idx += 256){
        int n0 = idx >> 3, sb = idx & 7;
        int v = bstart + n0;
        if (v < N){
            int hx = sb >> 1;
            float advx = a_d[(size_t)v*4 + hx];
            float shx = leaky(mxs[hx] + mxs[4+hx]);
            float eesl = __expf(leaky(a_s[(size_t)v*4 + hx] + advx) - shx);
            us8 g0 = gb[(size_t)v*8 + sb];
            float inv = 1.f/(acc[n0][64 + hx] + eesl);
            us8 px;
            #pragma unroll
            for (int j = 0; j < 8; j++){
                float valx = acc[n0][sb*8+j] + eesl * __half2float(__ushort_as_half(g0[j]));
                px[j] = __half_as_ushort(__float2half(valx * inv));
            }
            ((us8*)xg16)[(size_t)v*8 + sb] = px;
        }
    }
}

// ---------- fuse (MFMA): y = [Aj|xg] @ W, + bias + residual + LN + ReLU ----------
__global__ __launch_bounds__(256) void k_fuse(float* __restrict__ h,
        const __half* __restrict__ Aj16, const __half* __restrict__ xg16,
        const float* __restrict__ dinv, __half* __restrict__ h16,
        __half* __restrict__ ht16,
        const _Float16* __restrict__ Bfrag, const float* __restrict__ b2c,
        const float* __restrict__ ln_g, const float* __restrict__ ln_b, int N){
    int lane = threadIdx.x & 63;
    int q = lane >> 4, c = lane & 15;
    half8 B[4][4];
    const half8* Bp = (const half8*)Bfrag;
    #pragma unroll
    for (int t = 0; t < 4; t++)
        #pragma unroll
        for (int kk = 0; kk < 4; kk++)
            B[t][kk] = Bp[(t*4+kk)*64 + lane];
    float bj[4], lg[4], lb[4];
    #pragma unroll
    for (int t = 0; t < 4; t++){
        int n = t*16 + c;
        bj[t] = b2c[n]; lg[t] = ln_g[n]; lb[t] = ln_b[n];
    }
    int tiles = (N + 15) >> 4;
    int wid = (blockIdx.x*blockDim.x + threadIdx.x) >> 6;
    int nw  = (gridDim.x*blockDim.x) >> 6;
    for (int tile = wid; tile < tiles; tile += nw){
        int nb = tile << 4;
        int anode = nb + c; if (anode >= N) anode = N - 1;
        const half8* ap = (const half8*)(Aj16 + (size_t)anode*64);
        const half8* xp = (const half8*)(xg16 + (size_t)anode*64);
        half8 A0 = ap[q];
        half8 A1 = ap[4 + q];
        half8 A2 = xp[q];
        half8 A3 = xp[4 + q];
        f32x4 acc[4];
        #pragma unroll
        for (int t = 0; t < 4; t++){
            f32x4 z = {0.f, 0.f, 0.f, 0.f};
            z = __builtin_amdgcn_mfma_f32_16x16x32_f16(A0, B[t][0], z, 0, 0, 0);
            z = __builtin_amdgcn_mfma_f32_16x16x32_f16(A1, B[t][1], z, 0, 0, 0);
            z = __builtin_amdgcn_mfma_f32_16x16x32_f16(A2, B[t][2], z, 0, 0, 0);
            z = __builtin_amdgcn_mfma_f32_16x16x32_f16(A3, B[t][3], z, 0, 0, 0);
            acc[t] = z;
        }
        float y[4][4];     // [t][r]
        #pragma unroll
        for (int r = 0; r < 4; r++){
            int node = nb + q*4 + r;
            int nd = node < N ? node : N - 1;
            #pragma unroll
            for (int t = 0; t < 4; t++)
                y[t][r] = acc[t][r] + bj[t] + h[(size_t)nd*64 + t*16 + c];
        }
        #pragma unroll
        for (int r = 0; r < 4; r++){
            int node = nb + q*4 + r;
            float s = (y[0][r] + y[1][r]) + (y[2][r] + y[3][r]);
            #pragma unroll
            for (int o = 1; o < 16; o <<= 1) s += __shfl_xor(s, o);
            float mu = s * (1.f/64.f);
            float d0 = y[0][r]-mu, d1 = y[1][r]-mu, d2 = y[2][r]-mu, d3 = y[3][r]-mu;
            float var = (d0*d0 + d1*d1) + (d2*d2 + d3*d3);
            #pragma unroll
            for (int o = 1; o < 16; o <<= 1) var += __shfl_xor(var, o);
            var *= (1.f/64.f);
            float rstd = rsqrtf(var + LNEPS);
            if (node < N){
                float dvv = dinv[node];
                #pragma unroll
                for (int t = 0; t < 4; t++){
                    float out = (y[t][r]-mu)*rstd*lg[t] + lb[t];
                    out = out > 0.f ? out : 0.f;
                    h[(size_t)node*64 + t*16 + c] = out;
                    h16[(size_t)node*64 + t*16 + c] = __float2half(out);
                    ht16[(size_t)node*64 + t*16 + c] = __float2half(dvv*out);
                }
            }
        }
    }
}

// ---------- readout ----------
__global__ __launch_bounds__(256) void k_readout(const float* __restrict__ h,
        const float* __restrict__ W1, const float* __restrict__ b1,
        const float* __restrict__ W2, const float* __restrict__ b2,
        float* __restrict__ out, int N){
    __shared__ float W1t[64*32];
    for (int idx = threadIdx.x; idx < 2048; idx += 256){
        int k = idx >> 5, j = idx & 31;
        W1t[idx] = W1[j*64+k];
    }
    __syncthreads();
    int lane = threadIdx.x & 63;
    float w2  = (lane < 32) ? W2[lane] : 0.f;
    float b1v = (lane < 32) ? b1[lane] : 0.f;
    float b2v = b2[0];
    int wid = (blockIdx.x*blockDim.x + threadIdx.x) >> 6;
    int nw  = (gridDim.x*blockDim.x) >> 6;
    for (int v = wid; v < N; v += nw){
        float hj = h[(size_t)v*64+lane];
        float acc = b1v;
        #pragma unroll
        for (int k = 0; k < 64; k++){
            float hk = __shfl(hj, k);
            if (lane < 32) acc += hk * W1t[k*32+lane];
        }
        float h1 = acc > 0.f ? acc : 0.f;
        float p = h1 * w2;
        #pragma unroll
        for (int o = 1; o < 32; o <<= 1) p += __shfl_xor(p, o);
        if (lane == 0){
            float z = p + b2v;
            out[v] = 1.f/(1.f + __expf(-z));
        }
    }
}

extern "C" void kernel_launch(void* const* d_in, const int* in_sizes, int n_in,
                              void* d_out, int out_size, void* d_ws, size_t ws_size,
                              hipStream_t stream){
    const ushort_t* xs = (const ushort_t*)d_in[0];
    const int*      ei = (const int*)d_in[1];

    int N = in_sizes[0] / 64;
    int E = in_sizes[1] / 2;
    const int* row = ei;
    const int* col = ei + E;
    int NBK = (N + BWD - 1) / BWD;
    int segw = (N + SEGS - 1) / SEGS;

    size_t stageF = (size_t)2*E;
    size_t mirF   = (size_t)N*32;
    size_t aliasF = stageF > mirF ? stageF : mirF;

    float* f = (float*)d_ws;
    size_t o = 0;
    int*   flags = (int*)(f + o); o += 16;
    float* P     = f + o; o += P_TOTAL + 63;
    float* h     = f + o; o += (size_t)N*64;
    __half* h16  = (__half*)(f + o); o += mirF;
    __half* ht16 = (__half*)(f + o); o += mirF;
    __half* G16  = (__half*)(f + o); o += mirF;
    __half* Aj16 = (__half*)(f + o); size_t aoff = o; o += aliasF;
    __half* xg16 = (__half*)(f + o); size_t xoff = o; o += aliasF;
    uint2* stage_r = (uint2*)(f + aoff);
    uint2* stage_c = (uint2*)(f + xoff);
    float* a_s   = f + o; o += (size_t)N*4;
    float* a_d   = f + o; o += (size_t)N*4;
    float* mxs   = f + o; o += 16;
    float* bmax_s= f + o; o += 1024;
    float* bmax_d= f + o; o += 1024;
    float* dinv  = f + o; o += ((size_t)N + 15) & ~15ull;
    int* bcnt    = (int*)(f + o); o += 512;
    int* bptr_r  = (int*)(f + o); o += 512;
    int* bptr_c  = (int*)(f + o); o += 512;
    int* bcur_r  = (int*)(f + o); o += 512;
    int* bcur_c  = (int*)(f + o); o += 512;
    int* ptr_r   = (int*)(f + o); o += ((size_t)N*SEGS + 16 + 15) & ~15ull;
    int* ptr_c   = (int*)(f + o); o += ((size_t)N*SEGS + 16 + 15) & ~15ull;
    int* re_col  = (int*)(f + o); o += (size_t)E;
    int* ce_row  = (int*)(f + o); o += (size_t)E;
    float* W1c   = f + o; o += 3*4096;
    float* b2c   = f + o; o += 3*64;
    _Float16* Bfrag = (_Float16*)(f + o); o += 3*4096;   // 3*8192 fp16
    _Float16* Bg    = (_Float16*)(f + o); o += 3*2048;   // 3*4096 fp16

    const float* emb_W   = P + 0;
    const float* emb_b   = P + 4096;
    const float* e8_W    = P + 4160;
    const float* gat_W   = P + 16448;
    const float* att_src = P + 28736;
    const float* att_dst = P + 28928;
    const float* gat_b   = P + 29120;
    const float* fus_W   = P + 29312;
    const float* fus_b   = P + 53888;
    const float* ln_g    = P + 54080;
    const float* ln_b    = P + 54272;
    const float* r_W1    = P + 54464;
    const float* r_b1    = P + 56512;
    const float* r_W2    = P + 56544;
    const float* r_b2    = P + 56576;

    k_detect<<<1, 64, 0, stream>>>(d_in[0], d_in[2], d_in[4], d_in[5], d_in[6], d_in[7],
                                   d_in[9], d_in[13], d_in[15], d_in[11], flags);
    k_convert<<<(P_TOTAL+255)/256, 256, 0, stream>>>(
        d_in[2],d_in[3],d_in[4],d_in[5],d_in[6],d_in[7],d_in[8],d_in[9],
        d_in[10],d_in[11],d_in[12],d_in[13],d_in[14],d_in[15],d_in[16], flags, P);

    hipMemsetAsync(bcnt, 0, 512*sizeof(int), stream);
    kb_hist<<<256, 1024, 0, stream>>>(row, col, bcnt, NBK, E);
    kb_scan<<<2, 256, 0, stream>>>(bcnt, bptr_r, bptr_c, bcur_r, bcur_c, NBK, E);
    kb_bin<<<256, 1024, 0, stream>>>(row, col, bcur_r, stage_r, NBK, E);
    kb_bin<<<256, 1024, 0, stream>>>(col, row, bcur_c, stage_c, NBK, E);
    kb_place<<<NBK, 1024, 0, stream>>>(stage_r, bptr_r, ptr_r, re_col, dinv, 0, N, E, segw);
    kb_place<<<NBK, 1024, 0, stream>>>(stage_c, bptr_c, ptr_c, ce_row, dinv, 1, N, E, segw);

    k_prew<<<48, 256, 0, stream>>>(fus_W, e8_W, gat_b, fus_b, W1c, b2c);
    k_prewB<<<(3*8192+255)/256, 256, 0, stream>>>(W1c, fus_W, Bfrag);
    k_prewBg<<<(3*4096+255)/256, 256, 0, stream>>>(gat_W, Bg);
    k_embed<<<1024, 256, 0, stream>>>(xs, flags, emb_W, emb_b, dinv, h, h16, ht16, N);

    int npb = (N + 1023) >> 10;              // nodes per block (98 @ N=100k)
    if (npb > MAXNPB) npb = MAXNPB;
    int gblocks = (N + npb - 1) / npb;       // <=1024 -> single co-resident generation
    int tiles = (N + 15) / 16;
    int fgrid = (tiles + 7) / 8;
    for (int i = 0; i < 3; i++){
        k_gat_g<<<fgrid, 256, 0, stream>>>(h16, Bg + (size_t)i*4096,
                                           att_src + i*64, att_dst + i*64,
                                           G16, a_s, a_d, N);
        k_headmax1<<<256, 256, 0, stream>>>(a_s, a_d, bmax_s, bmax_d, N*4);
        k_headmax2<<<1, 64, 0, stream>>>(bmax_s, bmax_d, mxs, 256);
        k_gather<<<gblocks, 256, 0, stream>>>(ht16, G16, a_s, a_d, mxs, dinv,
                                              ptr_r, re_col, ptr_c, ce_row,
                                              Aj16, xg16, N, npb);
        k_fuse<<<fgrid, 256, 0, stream>>>(h, Aj16, xg16, dinv, h16, ht16,
                                          Bfrag + (size_t)i*8192, b2c + i*64,
                                          ln_g + i*64, ln_b + i*64, N);
    }
    k_readout<<<1024, 256, 0, stream>>>(h, r_W1, r_b1, r_W2, r_b2, (float*)d_out, N);
}

// Round 5
// 884.591 us; speedup vs baseline: 1.3274x; 1.3274x over previous
//
#include <hip/hip_runtime.h>
#include <hip/hip_bf16.h>
#include <hip/hip_fp16.h>

typedef __hip_bfloat16 bf16;
typedef unsigned short ushort_t;
typedef unsigned short us8 __attribute__((ext_vector_type(8)));
typedef _Float16 half8 __attribute__((ext_vector_type(8)));
typedef float f32x4 __attribute__((ext_vector_type(4)));

#define NEG 0.2f
#define LNEPS 1e-5f
#define BWD 512                 // CSR bucket width (nodes)

__device__ __forceinline__ int plaus(unsigned int lo){
    lo &= 0x7FFFu;
    if (lo == 0) return 1;
    unsigned int ex = (lo >> 7) & 0xFF;
    return (ex >= 100 && ex <= 140) ? 1 : 0;
}

__device__ __forceinline__ float decode_slot(const ushort_t* s, long long i, int fl){
    long long base = i << fl;
    unsigned int hi = s[base + fl];
    unsigned int lo = s[base];
    unsigned int bits = (hi << 16) | (lo * (unsigned int)fl);
    return __uint_as_float(bits);
}

// order-preserving float<->uint encoding for atomicMax on floats (incl. negatives)
__device__ __forceinline__ unsigned encf(float f){
    int b = __float_as_int(f);
    return (b >= 0) ? ((unsigned)b | 0x80000000u) : (unsigned)(~b);
}
__device__ __forceinline__ float decf(unsigned k){
    return (k & 0x80000000u) ? __uint_as_float(k & 0x7FFFFFFFu)
                             : __uint_as_float(~k);
}

// ---------- per-tensor dtype flags ----------
__global__ void k_detect(const void* t0, const void* t1, const void* t2, const void* t3,
                         const void* t4, const void* t5, const void* t6, const void* t7,
                         const void* t8, const void* lng, int* flags){
    int t = threadIdx.x;
    if (blockIdx.x != 0) return;
    if (t < 9){
        const void* ptrs[9] = {t0,t1,t2,t3,t4,t5,t6,t7,t8};
        const ushort_t* w = (const ushort_t*)ptrs[t];
        int all_bf = 1;
        for (int i = 0; i < 16; i++) all_bf &= plaus((unsigned int)w[i]);
        flags[t] = all_bf ? 0 : 1;
    } else if (t == 9){
        const ushort_t* w = (const ushort_t*)lng;
        flags[9] = (w[0] == 0x3F80u) ? 0 : 1;
    }
}

// ---------- stage params ----------
#define P_TOTAL 56577
__global__ void k_convert(const void* p0, const void* p1, const void* p2, const void* p3,
        const void* p4, const void* p5, const void* p6, const void* p7, const void* p8,
        const void* p9, const void* p10, const void* p11, const void* p12, const void* p13,
        const void* p14, const int* flags, float* P){
    int idx = blockIdx.x*blockDim.x + threadIdx.x;
    if (idx >= P_TOTAL) return;
    const int sizes[15] = {4096,64,12288,12288,192,192,192,24576,192,192,192,2048,32,32,1};
    const int fidx[15]  = {1,  -1,  2,    3,    4,  5,  -1, 6,    -1, 9,  -1, 7,   -1,8, -1};
    const void* ptrs[15] = {p0,p1,p2,p3,p4,p5,p6,p7,p8,p9,p10,p11,p12,p13,p14};
    int s = 0, base = 0;
    while (idx - base >= sizes[s]){ base += sizes[s]; s++; }
    int li = idx - base;
    int fi = fidx[s];
    int fl = (fi >= 0) ? flags[fi] : 0;
    P[idx] = decode_slot((const ushort_t*)ptrs[s], li, fl);
}

// ---------- bucketed CSR build ----------
__global__ __launch_bounds__(1024) void kb_hist(const int* __restrict__ row,
        const int* __restrict__ col, int* __restrict__ bcnt, int NBK, int E){
    __shared__ int lh[512];
    int t = threadIdx.x;
    for (int i = t; i < 2*NBK; i += 1024) lh[i] = 0;
    __syncthreads();
    for (long long e = (long long)blockIdx.x*1024 + t; e < E; e += (long long)gridDim.x*1024){
        atomicAdd(&lh[row[e] >> 9], 1);
        atomicAdd(&lh[NBK + (col[e] >> 9)], 1);
    }
    __syncthreads();
    for (int i = t; i < 2*NBK; i += 1024){
        int v = lh[i];
        if (v) atomicAdd(&bcnt[i], v);
    }
}

__global__ __launch_bounds__(256) void kb_scan(const int* __restrict__ bcnt,
        int* __restrict__ bptr_r, int* __restrict__ bptr_c,
        int* __restrict__ bcur_r, int* __restrict__ bcur_c, int NBK, int E){
    __shared__ int sh[256];
    int side = blockIdx.x;
    const int* c = bcnt + side*NBK;
    int* bp = side ? bptr_c : bptr_r;
    int* bc = side ? bcur_c : bcur_r;
    int t = threadIdx.x;
    int v = (t < NBK) ? c[t] : 0;
    sh[t] = v; __syncthreads();
    for (int off = 1; off < 256; off <<= 1){
        int add = (t >= off) ? sh[t-off] : 0;
        __syncthreads();
        sh[t] += add;
        __syncthreads();
    }
    if (t < NBK){ int e = sh[t] - v; bp[t] = e; bc[t] = e; }
    if (t == 0) bp[NBK] = E;
}

__global__ __launch_bounds__(1024) void kb_bin(const int* __restrict__ key,
        const int* __restrict__ pay, int* __restrict__ bcur,
        uint2* __restrict__ stage, int NBK, int E){
    __shared__ int lh[256], lbase[256];
    int t = threadIdx.x;
    for (long long tile = (long long)blockIdx.x*1024; tile < E; tile += (long long)gridDim.x*1024){
        for (int i = t; i < NBK; i += 1024) lh[i] = 0;
        __syncthreads();
        int e = (int)tile + t;
        int k = 0, p = 0, b = -1, rank = 0;
        if (e < E){
            k = key[e]; p = pay[e]; b = k >> 9;
            rank = atomicAdd(&lh[b], 1);
        }
        __syncthreads();
        for (int i = t; i < NBK; i += 1024){
            int c = lh[i];
            lbase[i] = c ? atomicAdd(&bcur[i], c) : 0;
        }
        __syncthreads();
        if (b >= 0) stage[lbase[b] + rank] = make_uint2((unsigned)k, (unsigned)p);
        __syncthreads();
    }
}

__global__ __launch_bounds__(1024) void kb_place(const uint2* __restrict__ stage,
        const int* __restrict__ bptr, int* __restrict__ ptr, int* __restrict__ outarr,
        float* __restrict__ dinv, int wantdinv, int N, int E){
    __shared__ int lcnt[BWD], lsc[BWD], lcur[BWD];
    int b = blockIdx.x;
    int s = bptr[b], e = bptr[b+1];
    int nbase = b << 9;
    int t = threadIdx.x;
    if (t < BWD) lcnt[t] = 0;
    __syncthreads();
    for (int i = s + t; i < e; i += 1024)
        atomicAdd(&lcnt[stage[i].x - nbase], 1);
    __syncthreads();
    if (t < BWD) lsc[t] = lcnt[t];
    __syncthreads();
    for (int off = 1; off < BWD; off <<= 1){
        int add = (t >= off && t < BWD) ? lsc[t-off] : 0;
        __syncthreads();
        if (t < BWD) lsc[t] += add;
        __syncthreads();
    }
    if (t < BWD){
        int node = nbase + t;
        int excl = lsc[t] - lcnt[t];
        lcur[t] = excl;
        if (node < N){
            ptr[node] = s + excl;
            if (wantdinv) dinv[node] = lcnt[t] > 0 ? rsqrtf((float)lcnt[t]) : 0.f;
        }
    }
    if (b == 0 && t == 0) ptr[N] = E;
    __syncthreads();
    for (int i = s + t; i < e; i += 1024){
        uint2 rec = stage[i];
        int pos = s + atomicAdd(&lcur[rec.x - nbase], 1);
        outarr[pos] = (int)rec.y;
    }
}

// ---------- precompute fused weights ----------
__global__ void k_prew(const float* __restrict__ fus_W, const float* __restrict__ e8_W,
                       const float* __restrict__ gat_b, const float* __restrict__ fus_b,
                       float* __restrict__ W1c, float* __restrict__ b2c){
    int t = blockIdx.x*blockDim.x + threadIdx.x;
    if (t < 3*4096){
        int i = t >> 12, jq = t & 4095, j = jq >> 6, q = jq & 63;
        const float* fw = fus_W + (size_t)i*64*128 + (size_t)j*128;
        const float* ew = e8_W + (size_t)i*4096;
        float acc = 0.f;
        for (int p = 0; p < 64; p++) acc += fw[p] * ew[p*64+q];
        W1c[t] = acc;
    }
    if (t < 3*64){
        int i = t >> 6, j = t & 63;
        const float* fw = fus_W + (size_t)i*64*128 + (size_t)j*128 + 64;
        float acc = fus_b[i*64+j];
        for (int p = 0; p < 64; p++) acc += gat_b[i*64+p] * fw[p];
        b2c[t] = acc;
    }
}

// ---------- pre-swizzle fusion weights into MFMA B-fragment order (fp16) ----------
__global__ void k_prewB(const float* __restrict__ W1c, const float* __restrict__ fus_W,
                        _Float16* __restrict__ Bfrag){
    int idx = blockIdx.x*blockDim.x + threadIdx.x;
    if (idx >= 3*8192) return;
    int i = idx / 8192; int rem = idx & 8191;
    int j = rem & 7, lane = (rem >> 3) & 63, kk = (rem >> 9) & 3, t = rem >> 11;
    int k = kk*32 + (lane >> 4)*8 + j;
    int n = t*16 + (lane & 15);
    float v = (k < 64) ? W1c[i*4096 + n*64 + k]
                       : fus_W[(size_t)i*8192 + n*128 + 64 + (k - 64)];
    Bfrag[idx] = (_Float16)v;
}

// ---------- pre-swizzle gat_W into B-frag order ----------
__global__ void k_prewBg(const float* __restrict__ gat_W, _Float16* __restrict__ Bg){
    int idx = blockIdx.x*blockDim.x + threadIdx.x;
    if (idx >= 3*4096) return;
    int i = idx / 4096; int rem = idx & 4095;
    int j = rem & 7, lane = (rem >> 3) & 63, kk = (rem >> 9) & 1, t = rem >> 10;
    int k = kk*32 + (lane >> 4)*8 + j;
    int n = t*16 + (lane & 15);
    Bg[idx] = (_Float16)gat_W[(size_t)i*4096 + k*64 + n];
}

// ---------- embedding: h fp32 + h16 + ht16 = dinv*h ----------
__global__ __launch_bounds__(256) void k_embed(const ushort_t* __restrict__ xs,
        const int* __restrict__ flags, const float* __restrict__ W,
        const float* __restrict__ b, const float* __restrict__ dinv,
        float* __restrict__ h, __half* __restrict__ h16, __half* __restrict__ ht16, int N){
    __shared__ float Wt[64*64];
    for (int idx = threadIdx.x; idx < 4096; idx += 256){
        int k = idx >> 6, j = idx & 63;
        Wt[idx] = W[j*64+k];
    }
    __syncthreads();
    int fl = flags[0];
    int lane = threadIdx.x & 63;
    int wid  = (blockIdx.x*blockDim.x + threadIdx.x) >> 6;
    int nw   = (gridDim.x*blockDim.x) >> 6;
    float bj = b[lane];
    for (int v = wid; v < N; v += nw){
        float xj = decode_slot(xs, (long long)v*64 + lane, fl);
        float acc = bj;
        #pragma unroll
        for (int k = 0; k < 64; k++) acc += __shfl(xj, k) * Wt[k*64+lane];
        h[(size_t)v*64 + lane] = acc;
        h16[(size_t)v*64 + lane] = __float2half(acc);
        ht16[(size_t)v*64 + lane] = __float2half(dinv[v]*acc);
    }
}

// ---------- per-layer (MFMA): G16 = h16 @ gat_W, head sums a_s/a_d ----------
// + fused per-head global max: block-reduced, 8 encoded atomicMax per block.
__global__ __launch_bounds__(256) void k_gat_g(const __half* __restrict__ h16,
        const _Float16* __restrict__ Bg, const float* __restrict__ att_src,
        const float* __restrict__ att_dst, __half* __restrict__ G16,
        float* __restrict__ a_s, float* __restrict__ a_d, float* __restrict__ mxs, int N){
    __shared__ float redm[4][8];
    int lane = threadIdx.x & 63;
    int wv = threadIdx.x >> 6;
    int q = lane >> 4, c = lane & 15;
    half8 B[4][2];
    const half8* Bp = (const half8*)Bg;
    #pragma unroll
    for (int t = 0; t < 4; t++)
        #pragma unroll
        for (int kk = 0; kk < 2; kk++)
            B[t][kk] = Bp[(t*2+kk)*64 + lane];
    float asv[4], adv[4];
    #pragma unroll
    for (int t = 0; t < 4; t++){
        asv[t] = att_src[t*16 + c];
        adv[t] = att_dst[t*16 + c];
    }
    float wms[4], wmd[4];
    #pragma unroll
    for (int t = 0; t < 4; t++){ wms[t] = -1e30f; wmd[t] = -1e30f; }
    int tiles = (N + 15) >> 4;
    int wid = (blockIdx.x*blockDim.x + threadIdx.x) >> 6;
    int nw  = (gridDim.x*blockDim.x) >> 6;
    for (int tile = wid; tile < tiles; tile += nw){
        int nb = tile << 4;
        int anode = nb + c; if (anode >= N) anode = N - 1;
        const half8* ap = (const half8*)(h16 + (size_t)anode*64);
        half8 A0 = ap[q];
        half8 A1 = ap[4 + q];
        f32x4 acc[4];
        #pragma unroll
        for (int t = 0; t < 4; t++){
            f32x4 z = {0.f, 0.f, 0.f, 0.f};
            z = __builtin_amdgcn_mfma_f32_16x16x32_f16(A0, B[t][0], z, 0, 0, 0);
            z = __builtin_amdgcn_mfma_f32_16x16x32_f16(A1, B[t][1], z, 0, 0, 0);
            acc[t] = z;
        }
        #pragma unroll
        for (int r = 0; r < 4; r++){
            int node = nb + q*4 + r;
            float tsv[4], tdv[4];
            #pragma unroll
            for (int t = 0; t < 4; t++){
                float s1 = acc[t][r]*asv[t];
                float s2 = acc[t][r]*adv[t];
                #pragma unroll
                for (int o = 1; o < 16; o <<= 1){
                    s1 += __shfl_xor(s1, o);
                    s2 += __shfl_xor(s2, o);
                }
                tsv[t] = s1; tdv[t] = s2;
                wms[t] = fmaxf(wms[t], s1);   // clamped dup nodes repeat real values
                wmd[t] = fmaxf(wmd[t], s2);
            }
            if (node < N){
                #pragma unroll
                for (int t = 0; t < 4; t++)
                    G16[(size_t)node*64 + t*16 + c] = __float2half(acc[t][r]);
                if (c == 0){
                    #pragma unroll
                    for (int t = 0; t < 4; t++){
                        a_s[node*4+t] = tsv[t];
                        a_d[node*4+t] = tdv[t];
                    }
                }
            }
        }
    }
    // wave reduce (cross-quad) then block reduce then 8 atomics
    #pragma unroll
    for (int t = 0; t < 4; t++){
        #pragma unroll
        for (int o = 16; o < 64; o <<= 1){
            wms[t] = fmaxf(wms[t], __shfl_xor(wms[t], o));
            wmd[t] = fmaxf(wmd[t], __shfl_xor(wmd[t], o));
        }
    }
    if (lane == 0){
        #pragma unroll
        for (int t = 0; t < 4; t++){
            redm[wv][t]   = wms[t];
            redm[wv][4+t] = wmd[t];
        }
    }
    __syncthreads();
    if (threadIdx.x < 8){
        float m = fmaxf(fmaxf(redm[0][threadIdx.x], redm[1][threadIdx.x]),
                        fmaxf(redm[2][threadIdx.x], redm[3][threadIdx.x]));
        atomicMax((unsigned*)mxs + threadIdx.x, encf(m));
    }
}

__device__ __forceinline__ float leaky(float t){ return t > 0.f ? t : NEG*t; }

// ---------- gather: 8 nodes/wave, 8 lanes/node, 16B loads (round-0 proven form) ----------
__global__ __launch_bounds__(256) void k_gather(const __half* __restrict__ ht16,
        const __half* __restrict__ G16,
        const float* __restrict__ a_s, const float* __restrict__ a_d,
        const float* __restrict__ mxs, const float* __restrict__ dinv,
        const int* __restrict__ row_ptr, const int* __restrict__ re_col,
        const int* __restrict__ col_ptr, const int* __restrict__ ce_row,
        __half* __restrict__ Aj16, __half* __restrict__ xg16, int N){
    int lane = threadIdx.x & 63;
    int grp  = lane >> 3;
    int sub  = lane & 7;
    int hh   = sub >> 1;
    int wid  = (blockIdx.x*blockDim.x + threadIdx.x) >> 6;
    int v    = wid*8 + grp;
    if (v >= N) return;
    const us8* htb = (const us8*)ht16;
    const us8* gb  = (const us8*)G16;
    const unsigned* mu = (const unsigned*)mxs;
    float sh = leaky(decf(mu[hh]) + decf(mu[4+hh]));
    int rs = row_ptr[v], re = row_ptr[v+1];
    float a0[8] = {0,0,0,0,0,0,0,0}, a1[8] = {0,0,0,0,0,0,0,0};
    float a2[8] = {0,0,0,0,0,0,0,0}, a3[8] = {0,0,0,0,0,0,0,0};
    int i = rs;
    for (; i + 3 < re; i += 4){
        us8 q0 = htb[(size_t)re_col[i]*8 + sub];
        us8 q1 = htb[(size_t)re_col[i+1]*8 + sub];
        us8 q2 = htb[(size_t)re_col[i+2]*8 + sub];
        us8 q3 = htb[(size_t)re_col[i+3]*8 + sub];
        #pragma unroll
        for (int j = 0; j < 8; j++){
            a0[j] += __half2float(__ushort_as_half(q0[j]));
            a1[j] += __half2float(__ushort_as_half(q1[j]));
            a2[j] += __half2float(__ushort_as_half(q2[j]));
            a3[j] += __half2float(__ushort_as_half(q3[j]));
        }
    }
    for (; i < re; i++){
        us8 q0 = htb[(size_t)re_col[i]*8 + sub];
        #pragma unroll
        for (int j = 0; j < 8; j++) a0[j] += __half2float(__ushort_as_half(q0[j]));
    }
    float dv = dinv[v];
    us8 pa;
    #pragma unroll
    for (int j = 0; j < 8; j++)
        pa[j] = __half_as_ushort(__float2half(dv*((a0[j]+a1[j]) + (a2[j]+a3[j]))));
    ((us8*)Aj16)[(size_t)v*8 + sub] = pa;
    float adv = a_d[v*4+hh];
    float eesl = __expf(leaky(a_s[v*4+hh] + adv) - sh);
    float s0 = eesl, s1 = 0.f, s2 = 0.f, s3 = 0.f;
    {
        us8 g0 = gb[(size_t)v*8 + sub];
        #pragma unroll
        for (int j = 0; j < 8; j++){
            a0[j] = eesl * __half2float(__ushort_as_half(g0[j]));
            a1[j] = 0.f; a2[j] = 0.f; a3[j] = 0.f;
        }
    }
    int cs = col_ptr[v], ce = col_ptr[v+1];
    i = cs;
    for (; i + 3 < ce; i += 4){
        int r0 = ce_row[i], r1 = ce_row[i+1], r2 = ce_row[i+2], r3 = ce_row[i+3];
        float e0 = __expf(leaky(a_s[r0*4+hh] + adv) - sh);
        float e1 = __expf(leaky(a_s[r1*4+hh] + adv) - sh);
        float e2 = __expf(leaky(a_s[r2*4+hh] + adv) - sh);
        float e3 = __expf(leaky(a_s[r3*4+hh] + adv) - sh);
        us8 q0 = gb[(size_t)r0*8 + sub];
        us8 q1 = gb[(size_t)r1*8 + sub];
        us8 q2 = gb[(size_t)r2*8 + sub];
        us8 q3 = gb[(size_t)r3*8 + sub];
        #pragma unroll
        for (int j = 0; j < 8; j++){
            a0[j] += e0 * __half2float(__ushort_as_half(q0[j]));
            a1[j] += e1 * __half2float(__ushort_as_half(q1[j]));
            a2[j] += e2 * __half2float(__ushort_as_half(q2[j]));
            a3[j] += e3 * __half2float(__ushort_as_half(q3[j]));
        }
        s0 += e0; s1 += e1; s2 += e2; s3 += e3;
    }
    for (; i < ce; i++){
        int r0 = ce_row[i];
        float e0 = __expf(leaky(a_s[r0*4+hh] + adv) - sh);
        us8 q0 = gb[(size_t)r0*8 + sub];
        #pragma unroll
        for (int j = 0; j < 8; j++) a0[j] += e0 * __half2float(__ushort_as_half(q0[j]));
        s0 += e0;
    }
    float inv = 1.f/((s0+s1)+(s2+s3));
    us8 px;
    #pragma unroll
    for (int j = 0; j < 8; j++)
        px[j] = __half_as_ushort(__float2half(((a0[j]+a1[j]) + (a2[j]+a3[j]))*inv));
    ((us8*)xg16)[(size_t)v*8 + sub] = px;
}

// ---------- fuse (MFMA): y = [Aj|xg] @ W, + bias + residual + LN + ReLU ----------
__global__ __launch_bounds__(256) void k_fuse(float* __restrict__ h,
        const __half* __restrict__ Aj16, const __half* __restrict__ xg16,
        const float* __restrict__ dinv, __half* __restrict__ h16,
        __half* __restrict__ ht16,
        const _Float16* __restrict__ Bfrag, const float* __restrict__ b2c,
        const float* __restrict__ ln_g, const float* __restrict__ ln_b, int N){
    int lane = threadIdx.x & 63;
    int q = lane >> 4, c = lane & 15;
    half8 B[4][4];
    const half8* Bp = (const half8*)Bfrag;
    #pragma unroll
    for (int t = 0; t < 4; t++)
        #pragma unroll
        for (int kk = 0; kk < 4; kk++)
            B[t][kk] = Bp[(t*4+kk)*64 + lane];
    float bj[4], lg[4], lb[4];
    #pragma unroll
    for (int t = 0; t < 4; t++){
        int n = t*16 + c;
        bj[t] = b2c[n]; lg[t] = ln_g[n]; lb[t] = ln_b[n];
    }
    int tiles = (N + 15) >> 4;
    int wid = (blockIdx.x*blockDim.x + threadIdx.x) >> 6;
    int nw  = (gridDim.x*blockDim.x) >> 6;
    for (int tile = wid; tile < tiles; tile += nw){
        int nb = tile << 4;
        int anode = nb + c; if (anode >= N) anode = N - 1;
        const half8* ap = (const half8*)(Aj16 + (size_t)anode*64);
        const half8* xp = (const half8*)(xg16 + (size_t)anode*64);
        half8 A0 = ap[q];
        half8 A1 = ap[4 + q];
        half8 A2 = xp[q];
        half8 A3 = xp[4 + q];
        f32x4 acc[4];
        #pragma unroll
        for (int t = 0; t < 4; t++){
            f32x4 z = {0.f, 0.f, 0.f, 0.f};
            z = __builtin_amdgcn_mfma_f32_16x16x32_f16(A0, B[t][0], z, 0, 0, 0);
            z = __builtin_amdgcn_mfma_f32_16x16x32_f16(A1, B[t][1], z, 0, 0, 0);
            z = __builtin_amdgcn_mfma_f32_16x16x32_f16(A2, B[t][2], z, 0, 0, 0);
            z = __builtin_amdgcn_mfma_f32_16x16x32_f16(A3, B[t][3], z, 0, 0, 0);
            acc[t] = z;
        }
        float y[4][4];     // [t][r]
        #pragma unroll
        for (int r = 0; r < 4; r++){
            int node = nb + q*4 + r;
            int nd = node < N ? node : N - 1;
            #pragma unroll
            for (int t = 0; t < 4; t++)
                y[t][r] = acc[t][r] + bj[t] + h[(size_t)nd*64 + t*16 + c];
        }
        #pragma unroll
        for (int r = 0; r < 4; r++){
            int node = nb + q*4 + r;
            float s = (y[0][r] + y[1][r]) + (y[2][r] + y[3][r]);
            #pragma unroll
            for (int o = 1; o < 16; o <<= 1) s += __shfl_xor(s, o);
            float mu = s * (1.f/64.f);
            float d0 = y[0][r]-mu, d1 = y[1][r]-mu, d2 = y[2][r]-mu, d3 = y[3][r]-mu;
            float var = (d0*d0 + d1*d1) + (d2*d2 + d3*d3);
            #pragma unroll
            for (int o = 1; o < 16; o <<= 1) var += __shfl_xor(var, o);
            var *= (1.f/64.f);
            float rstd = rsqrtf(var + LNEPS);
            if (node < N){
                float dvv = dinv[node];
                #pragma unroll
                for (int t = 0; t < 4; t++){
                    float out = (y[t][r]-mu)*rstd*lg[t] + lb[t];
                    out = out > 0.f ? out : 0.f;
                    h[(size_t)node*64 + t*16 + c] = out;
                    h16[(size_t)node*64 + t*16 + c] = __float2half(out);
                    ht16[(size_t)node*64 + t*16 + c] = __float2half(dvv*out);
                }
            }
        }
    }
}

// ---------- readout ----------
__global__ __launch_bounds__(256) void k_readout(const float* __restrict__ h,
        const float* __restrict__ W1, const float* __restrict__ b1,
        const float* __restrict__ W2, const float* __restrict__ b2,
        float* __restrict__ out, int N){
    __shared__ float W1t[64*32];
    for (int idx = threadIdx.x; idx < 2048; idx += 256){
        int k = idx >> 5, j = idx & 31;
        W1t[idx] = W1[j*64+k];
    }
    __syncthreads();
    int lane = threadIdx.x & 63;
    float w2  = (lane < 32) ? W2[lane] : 0.f;
    float b1v = (lane < 32) ? b1[lane] : 0.f;
    float b2v = b2[0];
    int wid = (blockIdx.x*blockDim.x + threadIdx.x) >> 6;
    int nw  = (gridDim.x*blockDim.x) >> 6;
    for (int v = wid; v < N; v += nw){
        float hj = h[(size_t)v*64+lane];
        float acc = b1v;
        #pragma unroll
        for (int k = 0; k < 64; k++){
            float hk = __shfl(hj, k);
            if (lane < 32) acc += hk * W1t[k*32+lane];
        }
        float h1 = acc > 0.f ? acc : 0.f;
        float p = h1 * w2;
        #pragma unroll
        for (int o = 1; o < 32; o <<= 1) p += __shfl_xor(p, o);
        if (lane == 0){
            float z = p + b2v;
            out[v] = 1.f/(1.f + __expf(-z));
        }
    }
}

extern "C" void kernel_launch(void* const* d_in, const int* in_sizes, int n_in,
                              void* d_out, int out_size, void* d_ws, size_t ws_size,
                              hipStream_t stream){
    const ushort_t* xs = (const ushort_t*)d_in[0];
    const int*      ei = (const int*)d_in[1];

    int N = in_sizes[0] / 64;
    int E = in_sizes[1] / 2;
    const int* row = ei;
    const int* col = ei + E;
    int NBK = (N + BWD - 1) / BWD;

    size_t stageF = (size_t)2*E;
    size_t mirF   = (size_t)N*32;
    size_t aliasF = stageF > mirF ? stageF : mirF;

    float* f = (float*)d_ws;
    size_t o = 0;
    int*   flags = (int*)(f + o); o += 16;
    float* P     = f + o; o += P_TOTAL + 63;
    float* h     = f + o; o += (size_t)N*64;
    __half* h16  = (__half*)(f + o); o += mirF;
    __half* ht16 = (__half*)(f + o); o += mirF;
    __half* G16  = (__half*)(f + o); o += mirF;
    __half* Aj16 = (__half*)(f + o); size_t aoff = o; o += aliasF;
    __half* xg16 = (__half*)(f + o); size_t xoff = o; o += aliasF;
    uint2* stage_r = (uint2*)(f + aoff);
    uint2* stage_c = (uint2*)(f + xoff);
    float* a_s   = f + o; o += (size_t)N*4;
    float* a_d   = f + o; o += (size_t)N*4;
    float* mxs   = f + o; o += 16;
    float* dinv  = f + o; o += ((size_t)N + 15) & ~15ull;
    int* bcnt    = (int*)(f + o); o += 512;
    int* bptr_r  = (int*)(f + o); o += 512;
    int* bptr_c  = (int*)(f + o); o += 512;
    int* bcur_r  = (int*)(f + o); o += 512;
    int* bcur_c  = (int*)(f + o); o += 512;
    int* ptr_r   = (int*)(f + o); o += ((size_t)N + 16) & ~15ull;
    int* ptr_c   = (int*)(f + o); o += ((size_t)N + 16) & ~15ull;
    int* re_col  = (int*)(f + o); o += (size_t)E;
    int* ce_row  = (int*)(f + o); o += (size_t)E;
    float* W1c   = f + o; o += 3*4096;
    float* b2c   = f + o; o += 3*64;
    _Float16* Bfrag = (_Float16*)(f + o); o += 3*4096;   // 3*8192 fp16
    _Float16* Bg    = (_Float16*)(f + o); o += 3*2048;   // 3*4096 fp16

    const float* emb_W   = P + 0;
    const float* emb_b   = P + 4096;
    const float* e8_W    = P + 4160;
    const float* gat_W   = P + 16448;
    const float* att_src = P + 28736;
    const float* att_dst = P + 28928;
    const float* gat_b   = P + 29120;
    const float* fus_W   = P + 29312;
    const float* fus_b   = P + 53888;
    const float* ln_g    = P + 54080;
    const float* ln_b    = P + 54272;
    const float* r_W1    = P + 54464;
    const float* r_b1    = P + 56512;
    const float* r_W2    = P + 56544;
    const float* r_b2    = P + 56576;

    k_detect<<<1, 64, 0, stream>>>(d_in[0], d_in[2], d_in[4], d_in[5], d_in[6], d_in[7],
                                   d_in[9], d_in[13], d_in[15], d_in[11], flags);
    k_convert<<<(P_TOTAL+255)/256, 256, 0, stream>>>(
        d_in[2],d_in[3],d_in[4],d_in[5],d_in[6],d_in[7],d_in[8],d_in[9],
        d_in[10],d_in[11],d_in[12],d_in[13],d_in[14],d_in[15],d_in[16], flags, P);

    hipMemsetAsync(bcnt, 0, 512*sizeof(int), stream);
    kb_hist<<<256, 1024, 0, stream>>>(row, col, bcnt, NBK, E);
    kb_scan<<<2, 256, 0, stream>>>(bcnt, bptr_r, bptr_c, bcur_r, bcur_c, NBK, E);
    kb_bin<<<256, 1024, 0, stream>>>(row, col, bcur_r, stage_r, NBK, E);
    kb_bin<<<256, 1024, 0, stream>>>(col, row, bcur_c, stage_c, NBK, E);
    kb_place<<<NBK, 1024, 0, stream>>>(stage_r, bptr_r, ptr_r, re_col, dinv, 0, N, E);
    kb_place<<<NBK, 1024, 0, stream>>>(stage_c, bptr_c, ptr_c, ce_row, dinv, 1, N, E);

    k_prew<<<48, 256, 0, stream>>>(fus_W, e8_W, gat_b, fus_b, W1c, b2c);
    k_prewB<<<(3*8192+255)/256, 256, 0, stream>>>(W1c, fus_W, Bfrag);
    k_prewBg<<<(3*4096+255)/256, 256, 0, stream>>>(gat_W, Bg);
    k_embed<<<1024, 256, 0, stream>>>(xs, flags, emb_W, emb_b, dinv, h, h16, ht16, N);

    int ggrid = (N + 31) / 32;
    int tiles = (N + 15) / 16;
    int fgrid = (tiles + 7) / 8;
    for (int i = 0; i < 3; i++){
        hipMemsetAsync(mxs, 0, 8*sizeof(unsigned), stream);   // encoded -inf
        k_gat_g<<<fgrid, 256, 0, stream>>>(h16, Bg + (size_t)i*4096,
                                           att_src + i*64, att_dst + i*64,
                                           G16, a_s, a_d, mxs, N);
        k_gather<<<ggrid, 256, 0, stream>>>(ht16, G16, a_s, a_d, mxs, dinv,
                                            ptr_r, re_col, ptr_c, ce_row,
                                            Aj16, xg16, N);
        k_fuse<<<fgrid, 256, 0, stream>>>(h, Aj16, xg16, dinv, h16, ht16,
                                          Bfrag + (size_t)i*8192, b2c + i*64,
                                          ln_g + i*64, ln_b + i*64, N);
    }
    k_readout<<<1024, 256, 0, stream>>>(h, r_W1, r_b1, r_W2, r_b2, (float*)d_out, N);
}

// Round 6
// 859.788 us; speedup vs baseline: 1.3657x; 1.0288x over previous
//
#include <hip/hip_runtime.h>
#include <hip/hip_bf16.h>
#include <hip/hip_fp16.h>

typedef __hip_bfloat16 bf16;
typedef unsigned short ushort_t;
typedef unsigned short us8 __attribute__((ext_vector_type(8)));
typedef _Float16 half8 __attribute__((ext_vector_type(8)));
typedef float f32x4 __attribute__((ext_vector_type(4)));

#define NEG 0.2f
#define LNEPS 1e-5f
#define BWD 512                 // CSR bucket width (nodes)

__device__ __forceinline__ int plaus(unsigned int lo){
    lo &= 0x7FFFu;
    if (lo == 0) return 1;
    unsigned int ex = (lo >> 7) & 0xFF;
    return (ex >= 100 && ex <= 140) ? 1 : 0;
}

__device__ __forceinline__ float decode_slot(const ushort_t* s, long long i, int fl){
    long long base = i << fl;
    unsigned int hi = s[base + fl];
    unsigned int lo = s[base];
    unsigned int bits = (hi << 16) | (lo * (unsigned int)fl);
    return __uint_as_float(bits);
}

// order-preserving float<->uint encoding for atomicMax on floats (incl. negatives)
__device__ __forceinline__ unsigned encf(float f){
    int b = __float_as_int(f);
    return (b >= 0) ? ((unsigned)b | 0x80000000u) : (unsigned)(~b);
}
__device__ __forceinline__ float decf(unsigned k){
    return (k & 0x80000000u) ? __uint_as_float(k & 0x7FFFFFFFu)
                             : __uint_as_float(~k);
}

// ---------- per-tensor dtype flags ----------
__global__ void k_detect(const void* t0, const void* t1, const void* t2, const void* t3,
                         const void* t4, const void* t5, const void* t6, const void* t7,
                         const void* t8, const void* lng, int* flags){
    int t = threadIdx.x;
    if (blockIdx.x != 0) return;
    if (t < 9){
        const void* ptrs[9] = {t0,t1,t2,t3,t4,t5,t6,t7,t8};
        const ushort_t* w = (const ushort_t*)ptrs[t];
        int all_bf = 1;
        for (int i = 0; i < 16; i++) all_bf &= plaus((unsigned int)w[i]);
        flags[t] = all_bf ? 0 : 1;
    } else if (t == 9){
        const ushort_t* w = (const ushort_t*)lng;
        flags[9] = (w[0] == 0x3F80u) ? 0 : 1;
    }
}

// ---------- stage params ----------
#define P_TOTAL 56577
__global__ void k_convert(const void* p0, const void* p1, const void* p2, const void* p3,
        const void* p4, const void* p5, const void* p6, const void* p7, const void* p8,
        const void* p9, const void* p10, const void* p11, const void* p12, const void* p13,
        const void* p14, const int* flags, float* P){
    int idx = blockIdx.x*blockDim.x + threadIdx.x;
    if (idx >= P_TOTAL) return;
    const int sizes[15] = {4096,64,12288,12288,192,192,192,24576,192,192,192,2048,32,32,1};
    const int fidx[15]  = {1,  -1,  2,    3,    4,  5,  -1, 6,    -1, 9,  -1, 7,   -1,8, -1};
    const void* ptrs[15] = {p0,p1,p2,p3,p4,p5,p6,p7,p8,p9,p10,p11,p12,p13,p14};
    int s = 0, base = 0;
    while (idx - base >= sizes[s]){ base += sizes[s]; s++; }
    int li = idx - base;
    int fi = fidx[s];
    int fl = (fi >= 0) ? flags[fi] : 0;
    P[idx] = decode_slot((const ushort_t*)ptrs[s], li, fl);
}

// ---------- bucketed CSR build ----------
__global__ __launch_bounds__(1024) void kb_hist(const int* __restrict__ row,
        const int* __restrict__ col, int* __restrict__ bcnt, int NBK, int E){
    __shared__ int lh[512];
    int t = threadIdx.x;
    for (int i = t; i < 2*NBK; i += 1024) lh[i] = 0;
    __syncthreads();
    for (long long e = (long long)blockIdx.x*1024 + t; e < E; e += (long long)gridDim.x*1024){
        atomicAdd(&lh[row[e] >> 9], 1);
        atomicAdd(&lh[NBK + (col[e] >> 9)], 1);
    }
    __syncthreads();
    for (int i = t; i < 2*NBK; i += 1024){
        int v = lh[i];
        if (v) atomicAdd(&bcnt[i], v);
    }
}

__global__ __launch_bounds__(256) void kb_scan(const int* __restrict__ bcnt,
        int* __restrict__ bptr_r, int* __restrict__ bptr_c,
        int* __restrict__ bcur_r, int* __restrict__ bcur_c, int NBK, int E){
    __shared__ int sh[256];
    int side = blockIdx.x;
    const int* c = bcnt + side*NBK;
    int* bp = side ? bptr_c : bptr_r;
    int* bc = side ? bcur_c : bcur_r;
    int t = threadIdx.x;
    int v = (t < NBK) ? c[t] : 0;
    sh[t] = v; __syncthreads();
    for (int off = 1; off < 256; off <<= 1){
        int add = (t >= off) ? sh[t-off] : 0;
        __syncthreads();
        sh[t] += add;
        __syncthreads();
    }
    if (t < NBK){ int e = sh[t] - v; bp[t] = e; bc[t] = e; }
    if (t == 0) bp[NBK] = E;
}

__global__ __launch_bounds__(1024) void kb_bin(const int* __restrict__ key,
        const int* __restrict__ pay, int* __restrict__ bcur,
        uint2* __restrict__ stage, int NBK, int E){
    __shared__ int lh[256], lbase[256];
    int t = threadIdx.x;
    for (long long tile = (long long)blockIdx.x*1024; tile < E; tile += (long long)gridDim.x*1024){
        for (int i = t; i < NBK; i += 1024) lh[i] = 0;
        __syncthreads();
        int e = (int)tile + t;
        int k = 0, p = 0, b = -1, rank = 0;
        if (e < E){
            k = key[e]; p = pay[e]; b = k >> 9;
            rank = atomicAdd(&lh[b], 1);
        }
        __syncthreads();
        for (int i = t; i < NBK; i += 1024){
            int c = lh[i];
            lbase[i] = c ? atomicAdd(&bcur[i], c) : 0;
        }
        __syncthreads();
        if (b >= 0) stage[lbase[b] + rank] = make_uint2((unsigned)k, (unsigned)p);
        __syncthreads();
    }
}

__global__ __launch_bounds__(1024) void kb_place(const uint2* __restrict__ stage,
        const int* __restrict__ bptr, int* __restrict__ ptr, int* __restrict__ outarr,
        float* __restrict__ dinv, int wantdinv, int N, int E){
    __shared__ int lcnt[BWD], lsc[BWD], lcur[BWD];
    int b = blockIdx.x;
    int s = bptr[b], e = bptr[b+1];
    int nbase = b << 9;
    int t = threadIdx.x;
    if (t < BWD) lcnt[t] = 0;
    __syncthreads();
    for (int i = s + t; i < e; i += 1024)
        atomicAdd(&lcnt[stage[i].x - nbase], 1);
    __syncthreads();
    if (t < BWD) lsc[t] = lcnt[t];
    __syncthreads();
    for (int off = 1; off < BWD; off <<= 1){
        int add = (t >= off && t < BWD) ? lsc[t-off] : 0;
        __syncthreads();
        if (t < BWD) lsc[t] += add;
        __syncthreads();
    }
    if (t < BWD){
        int node = nbase + t;
        int excl = lsc[t] - lcnt[t];
        lcur[t] = excl;
        if (node < N){
            ptr[node] = s + excl;
            if (wantdinv) dinv[node] = lcnt[t] > 0 ? rsqrtf((float)lcnt[t]) : 0.f;
        }
    }
    if (b == 0 && t == 0) ptr[N] = E;
    __syncthreads();
    for (int i = s + t; i < e; i += 1024){
        uint2 rec = stage[i];
        int pos = s + atomicAdd(&lcur[rec.x - nbase], 1);
        outarr[pos] = (int)rec.y;
    }
}

// ---------- precompute fused weights ----------
__global__ void k_prew(const float* __restrict__ fus_W, const float* __restrict__ e8_W,
                       const float* __restrict__ gat_b, const float* __restrict__ fus_b,
                       float* __restrict__ W1c, float* __restrict__ b2c){
    int t = blockIdx.x*blockDim.x + threadIdx.x;
    if (t < 3*4096){
        int i = t >> 12, jq = t & 4095, j = jq >> 6, q = jq & 63;
        const float* fw = fus_W + (size_t)i*64*128 + (size_t)j*128;
        const float* ew = e8_W + (size_t)i*4096;
        float acc = 0.f;
        for (int p = 0; p < 64; p++) acc += fw[p] * ew[p*64+q];
        W1c[t] = acc;
    }
    if (t < 3*64){
        int i = t >> 6, j = t & 63;
        const float* fw = fus_W + (size_t)i*64*128 + (size_t)j*128 + 64;
        float acc = fus_b[i*64+j];
        for (int p = 0; p < 64; p++) acc += gat_b[i*64+p] * fw[p];
        b2c[t] = acc;
    }
}

// ---------- pre-swizzle fusion weights into MFMA B-fragment order (fp16) ----------
__global__ void k_prewB(const float* __restrict__ W1c, const float* __restrict__ fus_W,
                        _Float16* __restrict__ Bfrag){
    int idx = blockIdx.x*blockDim.x + threadIdx.x;
    if (idx >= 3*8192) return;
    int i = idx / 8192; int rem = idx & 8191;
    int j = rem & 7, lane = (rem >> 3) & 63, kk = (rem >> 9) & 3, t = rem >> 11;
    int k = kk*32 + (lane >> 4)*8 + j;
    int n = t*16 + (lane & 15);
    float v = (k < 64) ? W1c[i*4096 + n*64 + k]
                       : fus_W[(size_t)i*8192 + n*128 + 64 + (k - 64)];
    Bfrag[idx] = (_Float16)v;
}

// ---------- pre-swizzle gat_W into B-frag order: 5 t-tiles x 2 kk-steps ----------
// t=0..3: G columns. t=4: columns 0..7 = att-folded projections
// (col 2h = gat_W[:,h-block]@att_src[h], col 2h+1 = @att_dst[h]), cols 8..15 zero.
__global__ void k_prewBg(const float* __restrict__ gat_W, const float* __restrict__ att_src,
                         const float* __restrict__ att_dst, _Float16* __restrict__ Bg){
    int idx = blockIdx.x*blockDim.x + threadIdx.x;
    if (idx >= 3*5120) return;
    int i = idx / 5120; int rem = idx % 5120;
    int j = rem & 7, lane = (rem >> 3) & 63, kk = (rem >> 9) & 1, t = rem >> 10;
    int k = kk*32 + (lane >> 4)*8 + j;
    int nn = lane & 15;
    float v;
    if (t < 4){
        v = gat_W[(size_t)i*4096 + k*64 + (t*16 + nn)];
    } else if (nn < 8){
        int hx = nn >> 1;
        const float* att = (nn & 1) ? att_dst : att_src;
        float acc = 0.f;
        for (int c = 0; c < 16; c++)
            acc += gat_W[(size_t)i*4096 + k*64 + hx*16 + c] * att[i*64 + hx*16 + c];
        v = acc;
    } else {
        v = 0.f;
    }
    Bg[idx] = (_Float16)v;
}

// ---------- embedding: h16 + ht16 = dinv*h (fp32 h mirror dropped) ----------
__global__ __launch_bounds__(256) void k_embed(const ushort_t* __restrict__ xs,
        const int* __restrict__ flags, const float* __restrict__ W,
        const float* __restrict__ b, const float* __restrict__ dinv,
        __half* __restrict__ h16, __half* __restrict__ ht16, float* __restrict__ mxs, int N){
    __shared__ float Wt[64*64];
    if (blockIdx.x == 0 && threadIdx.x < 8) ((unsigned*)mxs)[threadIdx.x] = 0u;  // encoded -inf
    for (int idx = threadIdx.x; idx < 4096; idx += 256){
        int k = idx >> 6, j = idx & 63;
        Wt[idx] = W[j*64+k];
    }
    __syncthreads();
    int fl = flags[0];
    int lane = threadIdx.x & 63;
    int wid  = (blockIdx.x*blockDim.x + threadIdx.x) >> 6;
    int nw   = (gridDim.x*blockDim.x) >> 6;
    float bj = b[lane];
    for (int v = wid; v < N; v += nw){
        float xj = decode_slot(xs, (long long)v*64 + lane, fl);
        float acc = bj;
        #pragma unroll
        for (int k = 0; k < 64; k++) acc += __shfl(xj, k) * Wt[k*64+lane];
        h16[(size_t)v*64 + lane] = __float2half(acc);
        ht16[(size_t)v*64 + lane] = __float2half(dinv[v]*acc);
    }
}

// ---------- per-layer (MFMA): G16 = h16 @ gat_W; a_s/a_d via att-folded 5th tile ----------
// acc[4] column c<8: c=2h -> a_s[.,h], c=2h+1 -> a_d[.,h]. Head max = per-lane fmax chain
// + cross-quad shfl + block reduce + 8 encoded atomicMax. No shuffle epilogue.
__global__ __launch_bounds__(256) void k_gat_g(const __half* __restrict__ h16,
        const _Float16* __restrict__ Bg, __half* __restrict__ G16,
        float* __restrict__ a_s, float* __restrict__ a_d, float* __restrict__ mxs, int N){
    __shared__ float redm[4][8];
    int lane = threadIdx.x & 63;
    int wv = threadIdx.x >> 6;
    int q = lane >> 4, c = lane & 15;
    half8 B[5][2];
    const half8* Bp = (const half8*)Bg;
    #pragma unroll
    for (int t = 0; t < 5; t++)
        #pragma unroll
        for (int kk = 0; kk < 2; kk++)
            B[t][kk] = Bp[(t*2+kk)*64 + lane];
    float lmax = -1e30f;
    int tiles = (N + 15) >> 4;
    int wid = (blockIdx.x*blockDim.x + threadIdx.x) >> 6;
    int nw  = (gridDim.x*blockDim.x) >> 6;
    for (int tile = wid; tile < tiles; tile += nw){
        int nb = tile << 4;
        int anode = nb + c; if (anode >= N) anode = N - 1;
        const half8* ap = (const half8*)(h16 + (size_t)anode*64);
        half8 A0 = ap[q];
        half8 A1 = ap[4 + q];
        f32x4 acc[5];
        #pragma unroll
        for (int t = 0; t < 5; t++){
            f32x4 z = {0.f, 0.f, 0.f, 0.f};
            z = __builtin_amdgcn_mfma_f32_16x16x32_f16(A0, B[t][0], z, 0, 0, 0);
            z = __builtin_amdgcn_mfma_f32_16x16x32_f16(A1, B[t][1], z, 0, 0, 0);
            acc[t] = z;
        }
        #pragma unroll
        for (int r = 0; r < 4; r++) lmax = fmaxf(lmax, acc[4][r]);
        #pragma unroll
        for (int r = 0; r < 4; r++){
            int node = nb + q*4 + r;
            if (node < N){
                #pragma unroll
                for (int t = 0; t < 4; t++)
                    G16[(size_t)node*64 + t*16 + c] = __float2half(acc[t][r]);
                if (c < 8){
                    int hx = c >> 1;
                    if (c & 1) a_d[node*4+hx] = acc[4][r];
                    else       a_s[node*4+hx] = acc[4][r];
                }
            }
        }
    }
    // cross-quad (same c, different q) then block reduce then 8 atomics
    lmax = fmaxf(lmax, __shfl_xor(lmax, 16));
    lmax = fmaxf(lmax, __shfl_xor(lmax, 32));
    if (lane < 8) redm[wv][lane] = lmax;
    __syncthreads();
    if (threadIdx.x < 8){
        float m = fmaxf(fmaxf(redm[0][threadIdx.x], redm[1][threadIdx.x]),
                        fmaxf(redm[2][threadIdx.x], redm[3][threadIdx.x]));
        int hx = threadIdx.x >> 1;
        int ix = (threadIdx.x & 1) ? 4 + hx : hx;
        atomicMax((unsigned*)mxs + ix, encf(m));
    }
}

__device__ __forceinline__ float leaky(float t){ return t > 0.f ? t : NEG*t; }

// ---------- gather: 8 nodes/wave, 8 lanes/node, 16B loads (round-0 proven form) ----------
__global__ __launch_bounds__(256) void k_gather(const __half* __restrict__ ht16,
        const __half* __restrict__ G16,
        const float* __restrict__ a_s, const float* __restrict__ a_d,
        const float* __restrict__ mxs, const float* __restrict__ dinv,
        const int* __restrict__ row_ptr, const int* __restrict__ re_col,
        const int* __restrict__ col_ptr, const int* __restrict__ ce_row,
        __half* __restrict__ Aj16, __half* __restrict__ xg16, int N){
    int lane = threadIdx.x & 63;
    int grp  = lane >> 3;
    int sub  = lane & 7;
    int hh   = sub >> 1;
    int wid  = (blockIdx.x*blockDim.x + threadIdx.x) >> 6;
    int v    = wid*8 + grp;
    if (v >= N) return;
    const us8* htb = (const us8*)ht16;
    const us8* gb  = (const us8*)G16;
    const unsigned* mu = (const unsigned*)mxs;
    float sh = leaky(decf(mu[hh]) + decf(mu[4+hh]));
    int rs = row_ptr[v], re = row_ptr[v+1];
    float a0[8] = {0,0,0,0,0,0,0,0}, a1[8] = {0,0,0,0,0,0,0,0};
    float a2[8] = {0,0,0,0,0,0,0,0}, a3[8] = {0,0,0,0,0,0,0,0};
    int i = rs;
    for (; i + 3 < re; i += 4){
        us8 q0 = htb[(size_t)re_col[i]*8 + sub];
        us8 q1 = htb[(size_t)re_col[i+1]*8 + sub];
        us8 q2 = htb[(size_t)re_col[i+2]*8 + sub];
        us8 q3 = htb[(size_t)re_col[i+3]*8 + sub];
        #pragma unroll
        for (int j = 0; j < 8; j++){
            a0[j] += __half2float(__ushort_as_half(q0[j]));
            a1[j] += __half2float(__ushort_as_half(q1[j]));
            a2[j] += __half2float(__ushort_as_half(q2[j]));
            a3[j] += __half2float(__ushort_as_half(q3[j]));
        }
    }
    for (; i < re; i++){
        us8 q0 = htb[(size_t)re_col[i]*8 + sub];
        #pragma unroll
        for (int j = 0; j < 8; j++) a0[j] += __half2float(__ushort_as_half(q0[j]));
    }
    float dv = dinv[v];
    us8 pa;
    #pragma unroll
    for (int j = 0; j < 8; j++)
        pa[j] = __half_as_ushort(__float2half(dv*((a0[j]+a1[j]) + (a2[j]+a3[j]))));
    ((us8*)Aj16)[(size_t)v*8 + sub] = pa;
    float adv = a_d[v*4+hh];
    float eesl = __expf(leaky(a_s[v*4+hh] + adv) - sh);
    float s0 = eesl, s1 = 0.f, s2 = 0.f, s3 = 0.f;
    {
        us8 g0 = gb[(size_t)v*8 + sub];
        #pragma unroll
        for (int j = 0; j < 8; j++){
            a0[j] = eesl * __half2float(__ushort_as_half(g0[j]));
            a1[j] = 0.f; a2[j] = 0.f; a3[j] = 0.f;
        }
    }
    int cs = col_ptr[v], ce = col_ptr[v+1];
    i = cs;
    for (; i + 3 < ce; i += 4){
        int r0 = ce_row[i], r1 = ce_row[i+1], r2 = ce_row[i+2], r3 = ce_row[i+3];
        float e0 = __expf(leaky(a_s[r0*4+hh] + adv) - sh);
        float e1 = __expf(leaky(a_s[r1*4+hh] + adv) - sh);
        float e2 = __expf(leaky(a_s[r2*4+hh] + adv) - sh);
        float e3 = __expf(leaky(a_s[r3*4+hh] + adv) - sh);
        us8 q0 = gb[(size_t)r0*8 + sub];
        us8 q1 = gb[(size_t)r1*8 + sub];
        us8 q2 = gb[(size_t)r2*8 + sub];
        us8 q3 = gb[(size_t)r3*8 + sub];
        #pragma unroll
        for (int j = 0; j < 8; j++){
            a0[j] += e0 * __half2float(__ushort_as_half(q0[j]));
            a1[j] += e1 * __half2float(__ushort_as_half(q1[j]));
            a2[j] += e2 * __half2float(__ushort_as_half(q2[j]));
            a3[j] += e3 * __half2float(__ushort_as_half(q3[j]));
        }
        s0 += e0; s1 += e1; s2 += e2; s3 += e3;
    }
    for (; i < ce; i++){
        int r0 = ce_row[i];
        float e0 = __expf(leaky(a_s[r0*4+hh] + adv) - sh);
        us8 q0 = gb[(size_t)r0*8 + sub];
        #pragma unroll
        for (int j = 0; j < 8; j++) a0[j] += e0 * __half2float(__ushort_as_half(q0[j]));
        s0 += e0;
    }
    float inv = 1.f/((s0+s1)+(s2+s3));
    us8 px;
    #pragma unroll
    for (int j = 0; j < 8; j++)
        px[j] = __half_as_ushort(__float2half(((a0[j]+a1[j]) + (a2[j]+a3[j]))*inv));
    ((us8*)xg16)[(size_t)v*8 + sub] = px;
}

// ---------- fuse (MFMA): y = [Aj|xg] @ W, + bias + residual(h16) + LN + ReLU ----------
// also re-arms mxs (encoded -inf) for the next layer's k_gat_g.
__global__ __launch_bounds__(256) void k_fuse(
        const __half* __restrict__ Aj16, const __half* __restrict__ xg16,
        const float* __restrict__ dinv, __half* __restrict__ h16,
        __half* __restrict__ ht16,
        const _Float16* __restrict__ Bfrag, const float* __restrict__ b2c,
        const float* __restrict__ ln_g, const float* __restrict__ ln_b,
        float* __restrict__ mxs, int N){
    if (blockIdx.x == 0 && threadIdx.x < 8) ((unsigned*)mxs)[threadIdx.x] = 0u;
    int lane = threadIdx.x & 63;
    int q = lane >> 4, c = lane & 15;
    half8 B[4][4];
    const half8* Bp = (const half8*)Bfrag;
    #pragma unroll
    for (int t = 0; t < 4; t++)
        #pragma unroll
        for (int kk = 0; kk < 4; kk++)
            B[t][kk] = Bp[(t*4+kk)*64 + lane];
    float bj[4], lg[4], lb[4];
    #pragma unroll
    for (int t = 0; t < 4; t++){
        int n = t*16 + c;
        bj[t] = b2c[n]; lg[t] = ln_g[n]; lb[t] = ln_b[n];
    }
    int tiles = (N + 15) >> 4;
    int wid = (blockIdx.x*blockDim.x + threadIdx.x) >> 6;
    int nw  = (gridDim.x*blockDim.x) >> 6;
    for (int tile = wid; tile < tiles; tile += nw){
        int nb = tile << 4;
        int anode = nb + c; if (anode >= N) anode = N - 1;
        const half8* ap = (const half8*)(Aj16 + (size_t)anode*64);
        const half8* xp = (const half8*)(xg16 + (size_t)anode*64);
        half8 A0 = ap[q];
        half8 A1 = ap[4 + q];
        half8 A2 = xp[q];
        half8 A3 = xp[4 + q];
        f32x4 acc[4];
        #pragma unroll
        for (int t = 0; t < 4; t++){
            f32x4 z = {0.f, 0.f, 0.f, 0.f};
            z = __builtin_amdgcn_mfma_f32_16x16x32_f16(A0, B[t][0], z, 0, 0, 0);
            z = __builtin_amdgcn_mfma_f32_16x16x32_f16(A1, B[t][1], z, 0, 0, 0);
            z = __builtin_amdgcn_mfma_f32_16x16x32_f16(A2, B[t][2], z, 0, 0, 0);
            z = __builtin_amdgcn_mfma_f32_16x16x32_f16(A3, B[t][3], z, 0, 0, 0);
            acc[t] = z;
        }
        float y[4][4];     // [t][r]
        #pragma unroll
        for (int r = 0; r < 4; r++){
            int node = nb + q*4 + r;
            int nd = node < N ? node : N - 1;
            #pragma unroll
            for (int t = 0; t < 4; t++)
                y[t][r] = acc[t][r] + bj[t]
                        + __half2float(h16[(size_t)nd*64 + t*16 + c]);
        }
        #pragma unroll
        for (int r = 0; r < 4; r++){
            int node = nb + q*4 + r;
            float s = (y[0][r] + y[1][r]) + (y[2][r] + y[3][r]);
            #pragma unroll
            for (int o = 1; o < 16; o <<= 1) s += __shfl_xor(s, o);
            float mu = s * (1.f/64.f);
            float d0 = y[0][r]-mu, d1 = y[1][r]-mu, d2 = y[2][r]-mu, d3 = y[3][r]-mu;
            float var = (d0*d0 + d1*d1) + (d2*d2 + d3*d3);
            #pragma unroll
            for (int o = 1; o < 16; o <<= 1) var += __shfl_xor(var, o);
            var *= (1.f/64.f);
            float rstd = rsqrtf(var + LNEPS);
            if (node < N){
                float dvv = dinv[node];
                #pragma unroll
                for (int t = 0; t < 4; t++){
                    float out = (y[t][r]-mu)*rstd*lg[t] + lb[t];
                    out = out > 0.f ? out : 0.f;
                    h16[(size_t)node*64 + t*16 + c] = __float2half(out);
                    ht16[(size_t)node*64 + t*16 + c] = __float2half(dvv*out);
                }
            }
        }
    }
}

// ---------- readout (h16 input) ----------
__global__ __launch_bounds__(256) void k_readout(const __half* __restrict__ h16,
        const float* __restrict__ W1, const float* __restrict__ b1,
        const float* __restrict__ W2, const float* __restrict__ b2,
        float* __restrict__ out, int N){
    __shared__ float W1t[64*32];
    for (int idx = threadIdx.x; idx < 2048; idx += 256){
        int k = idx >> 5, j = idx & 31;
        W1t[idx] = W1[j*64+k];
    }
    __syncthreads();
    int lane = threadIdx.x & 63;
    float w2  = (lane < 32) ? W2[lane] : 0.f;
    float b1v = (lane < 32) ? b1[lane] : 0.f;
    float b2v = b2[0];
    int wid = (blockIdx.x*blockDim.x + threadIdx.x) >> 6;
    int nw  = (gridDim.x*blockDim.x) >> 6;
    for (int v = wid; v < N; v += nw){
        float hj = __half2float(h16[(size_t)v*64+lane]);
        float acc = b1v;
        #pragma unroll
        for (int k = 0; k < 64; k++){
            float hk = __shfl(hj, k);
            if (lane < 32) acc += hk * W1t[k*32+lane];
        }
        float h1 = acc > 0.f ? acc : 0.f;
        float p = h1 * w2;
        #pragma unroll
        for (int o = 1; o < 32; o <<= 1) p += __shfl_xor(p, o);
        if (lane == 0){
            float z = p + b2v;
            out[v] = 1.f/(1.f + __expf(-z));
        }
    }
}

extern "C" void kernel_launch(void* const* d_in, const int* in_sizes, int n_in,
                              void* d_out, int out_size, void* d_ws, size_t ws_size,
                              hipStream_t stream){
    const ushort_t* xs = (const ushort_t*)d_in[0];
    const int*      ei = (const int*)d_in[1];

    int N = in_sizes[0] / 64;
    int E = in_sizes[1] / 2;
    const int* row = ei;
    const int* col = ei + E;
    int NBK = (N + BWD - 1) / BWD;

    size_t stageF = (size_t)2*E;
    size_t mirF   = (size_t)N*32;
    size_t aliasF = stageF > mirF ? stageF : mirF;

    float* f = (float*)d_ws;
    size_t o = 0;
    int*   flags = (int*)(f + o); o += 16;
    float* P     = f + o; o += P_TOTAL + 63;
    __half* h16  = (__half*)(f + o); o += mirF;
    __half* ht16 = (__half*)(f + o); o += mirF;
    __half* G16  = (__half*)(f + o); o += mirF;
    __half* Aj16 = (__half*)(f + o); size_t aoff = o; o += aliasF;
    __half* xg16 = (__half*)(f + o); size_t xoff = o; o += aliasF;
    uint2* stage_r = (uint2*)(f + aoff);
    uint2* stage_c = (uint2*)(f + xoff);
    float* a_s   = f + o; o += (size_t)N*4;
    float* a_d   = f + o; o += (size_t)N*4;
    float* mxs   = f + o; o += 16;
    float* dinv  = f + o; o += ((size_t)N + 15) & ~15ull;
    int* bcnt    = (int*)(f + o); o += 512;
    int* bptr_r  = (int*)(f + o); o += 512;
    int* bptr_c  = (int*)(f + o); o += 512;
    int* bcur_r  = (int*)(f + o); o += 512;
    int* bcur_c  = (int*)(f + o); o += 512;
    int* ptr_r   = (int*)(f + o); o += ((size_t)N + 16) & ~15ull;
    int* ptr_c   = (int*)(f + o); o += ((size_t)N + 16) & ~15ull;
    int* re_col  = (int*)(f + o); o += (size_t)E;
    int* ce_row  = (int*)(f + o); o += (size_t)E;
    float* W1c   = f + o; o += 3*4096;
    float* b2c   = f + o; o += 3*64;
    _Float16* Bfrag = (_Float16*)(f + o); o += 3*4096;   // 3*8192 fp16
    _Float16* Bg    = (_Float16*)(f + o); o += 3*2560;   // 3*5120 fp16 (5 t-tiles)

    const float* emb_W   = P + 0;
    const float* emb_b   = P + 4096;
    const float* e8_W    = P + 4160;
    const float* gat_W   = P + 16448;
    const float* att_src = P + 28736;
    const float* att_dst = P + 28928;
    const float* gat_b   = P + 29120;
    const float* fus_W   = P + 29312;
    const float* fus_b   = P + 53888;
    const float* ln_g    = P + 54080;
    const float* ln_b    = P + 54272;
    const float* r_W1    = P + 54464;
    const float* r_b1    = P + 56512;
    const float* r_W2    = P + 56544;
    const float* r_b2    = P + 56576;

    k_detect<<<1, 64, 0, stream>>>(d_in[0], d_in[2], d_in[4], d_in[5], d_in[6], d_in[7],
                                   d_in[9], d_in[13], d_in[15], d_in[11], flags);
    k_convert<<<(P_TOTAL+255)/256, 256, 0, stream>>>(
        d_in[2],d_in[3],d_in[4],d_in[5],d_in[6],d_in[7],d_in[8],d_in[9],
        d_in[10],d_in[11],d_in[12],d_in[13],d_in[14],d_in[15],d_in[16], flags, P);

    hipMemsetAsync(bcnt, 0, 512*sizeof(int), stream);
    kb_hist<<<256, 1024, 0, stream>>>(row, col, bcnt, NBK, E);
    kb_scan<<<2, 256, 0, stream>>>(bcnt, bptr_r, bptr_c, bcur_r, bcur_c, NBK, E);
    kb_bin<<<256, 1024, 0, stream>>>(row, col, bcur_r, stage_r, NBK, E);
    kb_bin<<<256, 1024, 0, stream>>>(col, row, bcur_c, stage_c, NBK, E);
    kb_place<<<NBK, 1024, 0, stream>>>(stage_r, bptr_r, ptr_r, re_col, dinv, 0, N, E);
    kb_place<<<NBK, 1024, 0, stream>>>(stage_c, bptr_c, ptr_c, ce_row, dinv, 1, N, E);

    k_prew<<<48, 256, 0, stream>>>(fus_W, e8_W, gat_b, fus_b, W1c, b2c);
    k_prewB<<<(3*8192+255)/256, 256, 0, stream>>>(W1c, fus_W, Bfrag);
    k_prewBg<<<(3*5120+255)/256, 256, 0, stream>>>(gat_W, att_src, att_dst, Bg);
    k_embed<<<1024, 256, 0, stream>>>(xs, flags, emb_W, emb_b, dinv, h16, ht16, mxs, N);

    int ggrid = (N + 31) / 32;
    int tiles = (N + 15) / 16;
    int fgrid = (tiles + 7) / 8;
    for (int i = 0; i < 3; i++){
        k_gat_g<<<fgrid, 256, 0, stream>>>(h16, Bg + (size_t)i*5120,
                                           G16, a_s, a_d, mxs, N);
        k_gather<<<ggrid, 256, 0, stream>>>(ht16, G16, a_s, a_d, mxs, dinv,
                                            ptr_r, re_col, ptr_c, ce_row,
                                            Aj16, xg16, N);
        k_fuse<<<fgrid, 256, 0, stream>>>(Aj16, xg16, dinv, h16, ht16,
                                          Bfrag + (size_t)i*8192, b2c + i*64,
                                          ln_g + i*64, ln_b + i*64, mxs, N);
    }
    k_readout<<<1024, 256, 0, stream>>>(h16, r_W1, r_b1, r_W2, r_b2, (float*)d_out, N);
}